// Round 1
// baseline (4397.252 us; speedup 1.0000x reference)
//
#include <hip/hip_runtime.h>
#include <math.h>

#define N_NODES 50000
#define E_EDGES 1600000
#define IN_CH   34
#define NEG     0.2f

// ---------------------------------------------------------------------------
// Layer 1 node pre-pass: xw1 = x @ W1  [N,128]; al_src/al_dst [N,2];
// initialize den1/acc1 with the self-loop contribution.
// Block = 256 threads = 4 waves; each wave owns one (node, head): 2 nodes/iter.
// ---------------------------------------------------------------------------
__global__ __launch_bounds__(256) void k_node1(
    const float* __restrict__ x, const float* __restrict__ W1,
    const float* __restrict__ a_src, const float* __restrict__ a_dst,
    float* __restrict__ xw1, float* __restrict__ al_s, float* __restrict__ al_d,
    float* __restrict__ den, float* __restrict__ acc)
{
    __shared__ float sW[IN_CH * 128];   // 17.4 KB
    __shared__ float sas[128], sad[128];
    __shared__ float sx[2][IN_CH];
    const int tid = threadIdx.x;
    for (int i = tid; i < IN_CH * 128; i += 256) sW[i] = W1[i];
    if (tid < 128) { sas[tid] = a_src[tid]; sad[tid] = a_dst[tid]; }
    __syncthreads();

    const int base = blockIdx.x * 32;
    for (int it = 0; it < 16; ++it) {
        const int n0 = base + it * 2;
        __syncthreads();
        if (tid < 2 * IN_CH) {
            int r = tid / IN_CH, c = tid - r * IN_CH;
            int nn = n0 + r;
            sx[r][c] = (nn < N_NODES) ? x[nn * IN_CH + c] : 0.f;
        }
        __syncthreads();
        const int node = n0 + (tid >> 7);
        const int col  = tid & 127;          // col = h*64 + c
        const float* xr = sx[tid >> 7];
        float a = 0.f;
        #pragma unroll
        for (int k = 0; k < IN_CH; ++k) a += xr[k] * sW[k * 128 + col];

        // wave (64 lanes) == one (node, head): butterfly-reduce the logits
        float ps = a * sas[col], pd = a * sad[col];
        #pragma unroll
        for (int off = 32; off; off >>= 1) {
            ps += __shfl_xor(ps, off);
            pd += __shfl_xor(pd, off);
        }
        const float e = ps + pd;
        const float wself = expf(e > 0.f ? e : NEG * e);
        if (node < N_NODES) {
            xw1[node * 128 + col] = a;
            acc[node * 128 + col] = wself * a;       // self-loop init
            if ((col & 63) == 0) {
                int h = col >> 6;
                al_s[node * 2 + h] = ps;
                al_d[node * 2 + h] = pd;
                den[node * 2 + h]  = wself;           // self-loop init
            }
        }
    }
}

// ---------------------------------------------------------------------------
// Layer 1 edge scatter: 32 threads per edge, 4 channels each.
// acc[dst] += w * xw[src];  den[dst,h] += w
// ---------------------------------------------------------------------------
__global__ __launch_bounds__(256) void k_edge1(
    const int* __restrict__ srcA, const int* __restrict__ dstA,
    const float* __restrict__ xw1,
    const float* __restrict__ al_s, const float* __restrict__ al_d,
    float* __restrict__ den, float* __restrict__ acc)
{
    const int gid = blockIdx.x * 256 + threadIdx.x;
    const int e = gid >> 5;
    if (e >= E_EDGES) return;
    const int j = gid & 31;
    const int s = srcA[e], d = dstA[e];
    const int h = j >> 4;
    const float al = al_s[s * 2 + h] + al_d[d * 2 + h];
    const float w = expf(al > 0.f ? al : NEG * al);
    if ((j & 15) == 0) atomicAdd(&den[d * 2 + h], w);
    const int c4 = j << 2;
    const float4 xv = *reinterpret_cast<const float4*>(xw1 + s * 128 + c4);
    float* ap = acc + d * 128 + c4;
    atomicAdd(ap + 0, w * xv.x);
    atomicAdd(ap + 1, w * xv.y);
    atomicAdd(ap + 2, w * xv.z);
    atomicAdd(ap + 3, w * xv.w);
}

// Layer 1 finalize: h = relu(acc/den + b1)  (written over xw1 buffer)
__global__ __launch_bounds__(256) void k_fin1(
    const float* __restrict__ acc, const float* __restrict__ den,
    const float* __restrict__ b1, float* __restrict__ hbuf)
{
    const int gid = blockIdx.x * 256 + threadIdx.x;
    if (gid >= N_NODES * 128) return;
    const int n = gid >> 7, c = gid & 127;
    const float v = acc[gid] / den[n * 2 + (c >> 6)] + b1[c];
    hbuf[gid] = v > 0.f ? v : 0.f;
}

// ---------------------------------------------------------------------------
// Layer 2 node pre-pass: xw2 = h @ W2 [N,64]; single head.
// Block = 256 = 4 waves; each wave owns one node: 4 nodes/iter.
// ---------------------------------------------------------------------------
__global__ __launch_bounds__(256) void k_node2(
    const float* __restrict__ hbuf, const float* __restrict__ W2,
    const float* __restrict__ a_src, const float* __restrict__ a_dst,
    float* __restrict__ xw2, float* __restrict__ al_s, float* __restrict__ al_d,
    float* __restrict__ den, float* __restrict__ acc)
{
    __shared__ float sW[128 * 64];      // 32 KB
    __shared__ float sas[64], sad[64];
    __shared__ float sh[4][128];
    const int tid = threadIdx.x;
    for (int i = tid; i < 128 * 64; i += 256) sW[i] = W2[i];
    if (tid < 64) { sas[tid] = a_src[tid]; sad[tid] = a_dst[tid]; }
    __syncthreads();

    const int base = blockIdx.x * 64;
    for (int it = 0; it < 16; ++it) {
        const int n0 = base + it * 4;
        __syncthreads();
        for (int i = tid; i < 4 * 128; i += 256) {
            int r = i >> 7, c = i & 127;
            int nn = n0 + r;
            sh[r][c] = (nn < N_NODES) ? hbuf[nn * 128 + c] : 0.f;
        }
        __syncthreads();
        const int node = n0 + (tid >> 6);
        const int col  = tid & 63;
        const float* hr = sh[tid >> 6];
        float a = 0.f;
        #pragma unroll 8
        for (int k = 0; k < 128; ++k) a += hr[k] * sW[k * 64 + col];

        float ps = a * sas[col], pd = a * sad[col];
        #pragma unroll
        for (int off = 32; off; off >>= 1) {
            ps += __shfl_xor(ps, off);
            pd += __shfl_xor(pd, off);
        }
        const float e = ps + pd;
        const float wself = expf(e > 0.f ? e : NEG * e);
        if (node < N_NODES) {
            xw2[node * 64 + col] = a;
            acc[node * 64 + col] = wself * a;
            if (col == 0) { al_s[node] = ps; al_d[node] = pd; den[node] = wself; }
        }
    }
}

// Layer 2 edge scatter: 16 threads per edge, 4 channels each.
__global__ __launch_bounds__(256) void k_edge2(
    const int* __restrict__ srcA, const int* __restrict__ dstA,
    const float* __restrict__ xw2,
    const float* __restrict__ al_s, const float* __restrict__ al_d,
    float* __restrict__ den, float* __restrict__ acc)
{
    const int gid = blockIdx.x * 256 + threadIdx.x;
    const int e = gid >> 4;
    if (e >= E_EDGES) return;
    const int j = gid & 15;
    const int s = srcA[e], d = dstA[e];
    const float al = al_s[s] + al_d[d];
    const float w = expf(al > 0.f ? al : NEG * al);
    if (j == 0) atomicAdd(&den[d], w);
    const int c4 = j << 2;
    const float4 xv = *reinterpret_cast<const float4*>(xw2 + s * 64 + c4);
    float* ap = acc + d * 64 + c4;
    atomicAdd(ap + 0, w * xv.x);
    atomicAdd(ap + 1, w * xv.y);
    atomicAdd(ap + 2, w * xv.z);
    atomicAdd(ap + 3, w * xv.w);
}

// Layer 2 finalize: out = acc/den + b2   (heads=1 so mean == identity)
__global__ __launch_bounds__(256) void k_fin2(
    const float* __restrict__ acc, const float* __restrict__ den,
    const float* __restrict__ b2, float* __restrict__ out)
{
    const int gid = blockIdx.x * 256 + threadIdx.x;
    if (gid >= N_NODES * 64) return;
    const int n = gid >> 6, c = gid & 63;
    out[gid] = acc[gid] / den[n] + b2[c];
}

extern "C" void kernel_launch(void* const* d_in, const int* in_sizes, int n_in,
                              void* d_out, int out_size, void* d_ws, size_t ws_size,
                              hipStream_t stream)
{
    const float* x   = (const float*)d_in[0];
    const int*   ei  = (const int*)d_in[1];     // [2,E] int32 (JAX x64 disabled)
    const float* W1  = (const float*)d_in[2];
    const float* as1 = (const float*)d_in[3];
    const float* ad1 = (const float*)d_in[4];
    const float* b1  = (const float*)d_in[5];
    const float* W2  = (const float*)d_in[6];
    const float* as2 = (const float*)d_in[7];
    const float* ad2 = (const float*)d_in[8];
    const float* b2  = (const float*)d_in[9];
    float* out = (float*)d_out;

    const int* srcA = ei;
    const int* dstA = ei + E_EDGES;

    // Workspace layout (floats). Total 13.25M floats = 53 MB.
    float* ws    = (float*)d_ws;
    float* xw1   = ws;                    // 6.4M ; reused as hbuf after k_fin1
    float* acc1  = ws + 6400000;          // 6.4M ; reused as xw2+acc2 in layer 2
    float* al_s1 = ws + 12800000;         // 100K
    float* al_d1 = al_s1 + 100000;        // 100K
    float* den1  = al_d1 + 100000;        // 100K
    float* al_s2 = den1  + 100000;        // 50K
    float* al_d2 = al_s2 + 50000;         // 50K
    float* den2  = al_d2 + 50000;         // 50K
    float* hbuf  = xw1;                   // alias: xw1 dead after k_edge1
    float* xw2   = acc1;                  // alias: acc1 dead after k_fin1
    float* acc2  = acc1 + 3200000;

    hipLaunchKernelGGL(k_node1, dim3((N_NODES + 31) / 32), dim3(256), 0, stream,
                       x, W1, as1, ad1, xw1, al_s1, al_d1, den1, acc1);
    hipLaunchKernelGGL(k_edge1, dim3((E_EDGES * 32) / 256), dim3(256), 0, stream,
                       srcA, dstA, xw1, al_s1, al_d1, den1, acc1);
    hipLaunchKernelGGL(k_fin1, dim3((N_NODES * 128 + 255) / 256), dim3(256), 0, stream,
                       acc1, den1, b1, hbuf);
    hipLaunchKernelGGL(k_node2, dim3((N_NODES + 63) / 64), dim3(256), 0, stream,
                       hbuf, W2, as2, ad2, xw2, al_s2, al_d2, den2, acc2);
    hipLaunchKernelGGL(k_edge2, dim3((E_EDGES * 16) / 256), dim3(256), 0, stream,
                       srcA, dstA, xw2, al_s2, al_d2, den2, acc2);
    hipLaunchKernelGGL(k_fin2, dim3((N_NODES * 64 + 255) / 256), dim3(256), 0, stream,
                       acc2, den2, b2, out);
}

// Round 2
// 725.548 us; speedup vs baseline: 6.0606x; 6.0606x over previous
//
#include <hip/hip_runtime.h>
#include <math.h>

#define N_NODES 50000
#define E_EDGES 1600000
#define IN_CH   34
#define NEG     0.2f

// ---------------------------------------------------------------------------
// Sort phase: counting sort of edges by dst. rowptr doubles as histogram.
// ---------------------------------------------------------------------------
__global__ __launch_bounds__(256) void k_hist(
    const int* __restrict__ dstA, int* __restrict__ cnt)
{
    const int e = blockIdx.x * 256 + threadIdx.x;
    if (e < E_EDGES) atomicAdd(&cnt[dstA[e]], 1);
}

// One-block exclusive prefix sum over cnt[0..N) in place.
__global__ __launch_bounds__(1024) void k_scan(int* __restrict__ cnt)
{
    __shared__ int wsum[16];
    __shared__ int carry;
    const int tid = threadIdx.x;
    const int lane = tid & 63, wv = tid >> 6;
    if (tid == 0) carry = 0;
    __syncthreads();
    for (int base = 0; base < N_NODES; base += 1024) {
        const int i = base + tid;
        const int v = (i < N_NODES) ? cnt[i] : 0;
        int x = v;
        #pragma unroll
        for (int off = 1; off < 64; off <<= 1) {
            int y = __shfl_up(x, off);
            if (lane >= off) x += y;
        }
        if (lane == 63) wsum[wv] = x;
        __syncthreads();
        if (tid < 16) {
            int s = wsum[tid];
            #pragma unroll
            for (int off = 1; off < 16; off <<= 1) {
                int y = __shfl_up(s, off);
                if (tid >= off) s += y;
            }
            wsum[tid] = s;
        }
        __syncthreads();
        const int waveoff = (wv == 0) ? 0 : wsum[wv - 1];
        const int excl = carry + waveoff + (x - v);
        const int tot  = carry + wsum[15];
        __syncthreads();                 // everyone has read carry/wsum
        if (i < N_NODES) cnt[i] = excl;
        if (tid == 0) carry = tot;
        __syncthreads();
    }
}

// Place src of each edge into its dst segment. After this, rowptr[d] is the
// END of segment d (start is rowptr[d-1], or 0 for d==0).
__global__ __launch_bounds__(256) void k_scatter(
    const int* __restrict__ srcA, const int* __restrict__ dstA,
    int* __restrict__ rowptr, int* __restrict__ sorted_src)
{
    const int e = blockIdx.x * 256 + threadIdx.x;
    if (e >= E_EDGES) return;
    const int d = dstA[e];
    const int p = atomicAdd(&rowptr[d], 1);
    sorted_src[p] = srcA[e];
}

// ---------------------------------------------------------------------------
// Layer 1 node pre-pass: xw1 = x @ W1 [N,128]; attention logit halves [N,2].
// ---------------------------------------------------------------------------
__global__ __launch_bounds__(256) void k_node1(
    const float* __restrict__ x, const float* __restrict__ W1,
    const float* __restrict__ a_src, const float* __restrict__ a_dst,
    float* __restrict__ xw1, float* __restrict__ al_s, float* __restrict__ al_d)
{
    __shared__ float sW[IN_CH * 128];
    __shared__ float sas[128], sad[128];
    __shared__ float sx[2][IN_CH];
    const int tid = threadIdx.x;
    for (int i = tid; i < IN_CH * 128; i += 256) sW[i] = W1[i];
    if (tid < 128) { sas[tid] = a_src[tid]; sad[tid] = a_dst[tid]; }
    __syncthreads();

    const int base = blockIdx.x * 32;
    for (int it = 0; it < 16; ++it) {
        const int n0 = base + it * 2;
        __syncthreads();
        if (tid < 2 * IN_CH) {
            int r = tid / IN_CH, c = tid - r * IN_CH;
            int nn = n0 + r;
            sx[r][c] = (nn < N_NODES) ? x[nn * IN_CH + c] : 0.f;
        }
        __syncthreads();
        const int node = n0 + (tid >> 7);
        const int col  = tid & 127;          // col = h*64 + c
        const float* xr = sx[tid >> 7];
        float a = 0.f;
        #pragma unroll
        for (int k = 0; k < IN_CH; ++k) a += xr[k] * sW[k * 128 + col];

        float ps = a * sas[col], pd = a * sad[col];
        #pragma unroll
        for (int off = 32; off; off >>= 1) {
            ps += __shfl_xor(ps, off);
            pd += __shfl_xor(pd, off);
        }
        if (node < N_NODES) {
            xw1[node * 128 + col] = a;
            if ((col & 63) == 0) {
                int h = col >> 6;
                al_s[node * 2 + h] = ps;
                al_d[node * 2 + h] = pd;
            }
        }
    }
}

// ---------------------------------------------------------------------------
// Layer 1 gather: one wave per (node, head). Batch 64 edges: each lane
// precomputes one edge's (src, weight), broadcast via shfl, coalesced row
// reads of xw1. Fused finalize: h = relu(acc/den + b1).
// ---------------------------------------------------------------------------
__global__ __launch_bounds__(256) void k_gather1(
    const int* __restrict__ rowptr, const int* __restrict__ sorted_src,
    const float* __restrict__ xw1,
    const float* __restrict__ al_s, const float* __restrict__ al_d,
    const float* __restrict__ b1, float* __restrict__ hbuf)
{
    const int wid  = (blockIdx.x * 256 + threadIdx.x) >> 6;
    const int lane = threadIdx.x & 63;
    const int node = wid >> 1, h = wid & 1;
    if (node >= N_NODES) return;
    const int beg = (node == 0) ? 0 : rowptr[node - 1];
    const int end = rowptr[node];
    const int col = h * 64 + lane;

    const float ald = al_d[node * 2 + h];
    // self-loop contribution
    const float e0 = al_s[node * 2 + h] + ald;
    const float w0 = expf(e0 > 0.f ? e0 : NEG * e0);
    float acc = w0 * xw1[node * 128 + col];
    float den = w0;

    for (int base = beg; base < end; base += 64) {
        const int n = end - base;
        int   sv = 0;
        float wv = 0.f;
        if (lane < n) {
            sv = sorted_src[base + lane];
            float al = al_s[sv * 2 + h] + ald;
            wv = expf(al > 0.f ? al : NEG * al);
        }
        const int m = n < 64 ? n : 64;
        for (int j = 0; j < m; ++j) {
            const int   s = __shfl(sv, j);
            const float w = __shfl(wv, j);
            acc += w * xw1[s * 128 + col];
            den += w;
        }
    }
    const float v = acc / den + b1[col];
    hbuf[node * 128 + col] = v > 0.f ? v : 0.f;
}

// ---------------------------------------------------------------------------
// Layer 2 node pre-pass: xw2 = h @ W2 [N,64]; single head logits.
// ---------------------------------------------------------------------------
__global__ __launch_bounds__(256) void k_node2(
    const float* __restrict__ hbuf, const float* __restrict__ W2,
    const float* __restrict__ a_src, const float* __restrict__ a_dst,
    float* __restrict__ xw2, float* __restrict__ al_s, float* __restrict__ al_d)
{
    __shared__ float sW[128 * 64];
    __shared__ float sas[64], sad[64];
    __shared__ float sh[4][128];
    const int tid = threadIdx.x;
    for (int i = tid; i < 128 * 64; i += 256) sW[i] = W2[i];
    if (tid < 64) { sas[tid] = a_src[tid]; sad[tid] = a_dst[tid]; }
    __syncthreads();

    const int base = blockIdx.x * 64;
    for (int it = 0; it < 16; ++it) {
        const int n0 = base + it * 4;
        __syncthreads();
        for (int i = tid; i < 4 * 128; i += 256) {
            int r = i >> 7, c = i & 127;
            int nn = n0 + r;
            sh[r][c] = (nn < N_NODES) ? hbuf[nn * 128 + c] : 0.f;
        }
        __syncthreads();
        const int node = n0 + (tid >> 6);
        const int col  = tid & 63;
        const float* hr = sh[tid >> 6];
        float a = 0.f;
        #pragma unroll 8
        for (int k = 0; k < 128; ++k) a += hr[k] * sW[k * 64 + col];

        float ps = a * sas[col], pd = a * sad[col];
        #pragma unroll
        for (int off = 32; off; off >>= 1) {
            ps += __shfl_xor(ps, off);
            pd += __shfl_xor(pd, off);
        }
        if (node < N_NODES) {
            xw2[node * 64 + col] = a;
            if (col == 0) { al_s[node] = ps; al_d[node] = pd; }
        }
    }
}

// Layer 2 gather: one wave per node, fused finalize (mean over 1 head = id).
__global__ __launch_bounds__(256) void k_gather2(
    const int* __restrict__ rowptr, const int* __restrict__ sorted_src,
    const float* __restrict__ xw2,
    const float* __restrict__ al_s, const float* __restrict__ al_d,
    const float* __restrict__ b2, float* __restrict__ out)
{
    const int node = (blockIdx.x * 256 + threadIdx.x) >> 6;
    const int lane = threadIdx.x & 63;
    if (node >= N_NODES) return;
    const int beg = (node == 0) ? 0 : rowptr[node - 1];
    const int end = rowptr[node];

    const float ald = al_d[node];
    const float e0 = al_s[node] + ald;
    const float w0 = expf(e0 > 0.f ? e0 : NEG * e0);
    float acc = w0 * xw2[node * 64 + lane];
    float den = w0;

    for (int base = beg; base < end; base += 64) {
        const int n = end - base;
        int   sv = 0;
        float wv = 0.f;
        if (lane < n) {
            sv = sorted_src[base + lane];
            float al = al_s[sv] + ald;
            wv = expf(al > 0.f ? al : NEG * al);
        }
        const int m = n < 64 ? n : 64;
        for (int j = 0; j < m; ++j) {
            const int   s = __shfl(sv, j);
            const float w = __shfl(wv, j);
            acc += w * xw2[s * 64 + lane];
            den += w;
        }
    }
    out[node * 64 + lane] = acc / den + b2[lane];
}

extern "C" void kernel_launch(void* const* d_in, const int* in_sizes, int n_in,
                              void* d_out, int out_size, void* d_ws, size_t ws_size,
                              hipStream_t stream)
{
    const float* x   = (const float*)d_in[0];
    const int*   ei  = (const int*)d_in[1];
    const float* W1  = (const float*)d_in[2];
    const float* as1 = (const float*)d_in[3];
    const float* ad1 = (const float*)d_in[4];
    const float* b1  = (const float*)d_in[5];
    const float* W2  = (const float*)d_in[6];
    const float* as2 = (const float*)d_in[7];
    const float* ad2 = (const float*)d_in[8];
    const float* b2  = (const float*)d_in[9];
    float* out = (float*)d_out;

    const int* srcA = ei;
    const int* dstA = ei + E_EDGES;

    // Workspace layout (bytes), 16B-aligned. Total ~59.0 MB.
    char* ws = (char*)d_ws;
    int*   rowptr     = (int*)(ws);                    // (N+1) ints, pad 204800 B
    int*   sorted_src = (int*)(ws + 204800);           // 6.4 MB
    float* al_s1      = (float*)(ws + 6604800);        // 400 KB
    float* al_d1      = (float*)(ws + 7004800);        // 400 KB
    float* al_s2      = (float*)(ws + 7404800);        // 200 KB
    float* al_d2      = (float*)(ws + 7604800);        // 200 KB
    float* xw1        = (float*)(ws + 7804800);        // 25.6 MB (reused as xw2)
    float* hbuf       = (float*)(ws + 33404800);       // 25.6 MB; end 59,004,800
    float* xw2        = xw1;                            // xw1 dead after k_gather1

    hipMemsetAsync(rowptr, 0, (N_NODES + 1) * sizeof(int), stream);
    hipLaunchKernelGGL(k_hist, dim3(E_EDGES / 256), dim3(256), 0, stream,
                       dstA, rowptr);
    hipLaunchKernelGGL(k_scan, dim3(1), dim3(1024), 0, stream, rowptr);
    hipLaunchKernelGGL(k_scatter, dim3(E_EDGES / 256), dim3(256), 0, stream,
                       srcA, dstA, rowptr, sorted_src);

    hipLaunchKernelGGL(k_node1, dim3((N_NODES + 31) / 32), dim3(256), 0, stream,
                       x, W1, as1, ad1, xw1, al_s1, al_d1);
    hipLaunchKernelGGL(k_gather1, dim3((N_NODES * 2 * 64 + 255) / 256), dim3(256), 0, stream,
                       rowptr, sorted_src, xw1, al_s1, al_d1, b1, hbuf);
    hipLaunchKernelGGL(k_node2, dim3((N_NODES + 63) / 64), dim3(256), 0, stream,
                       hbuf, W2, as2, ad2, xw2, al_s2, al_d2);
    hipLaunchKernelGGL(k_gather2, dim3((N_NODES * 64 + 255) / 256), dim3(256), 0, stream,
                       rowptr, sorted_src, xw2, al_s2, al_d2, b2, out);
}

// Round 3
// 526.679 us; speedup vs baseline: 8.3490x; 1.3776x over previous
//
#include <hip/hip_runtime.h>
#include <math.h>

#define N_NODES 50000
#define E_EDGES 1600000
#define IN_CH   34
#define NEG     0.2f

static __device__ __forceinline__ unsigned short f2bf(float f) {
    unsigned int u = __float_as_uint(f);
    u += 0x7fffu + ((u >> 16) & 1u);          // round-to-nearest-even
    return (unsigned short)(u >> 16);
}
static __device__ __forceinline__ float bf2f(unsigned short s) {
    return __uint_as_float(((unsigned int)s) << 16);
}
static __device__ __forceinline__ float lrelu_exp(float e) {
    return expf(e > 0.f ? e : NEG * e);
}

// ---------------------------------------------------------------------------
// Counting sort of edges by dst. rowptr doubles as histogram.
// ---------------------------------------------------------------------------
__global__ __launch_bounds__(256) void k_hist(
    const int* __restrict__ dstA, int* __restrict__ cnt)
{
    const int e = blockIdx.x * 256 + threadIdx.x;
    if (e < E_EDGES) atomicAdd(&cnt[dstA[e]], 1);
}

__global__ __launch_bounds__(1024) void k_scan(int* __restrict__ cnt)
{
    __shared__ int wsum[16];
    __shared__ int carry;
    const int tid = threadIdx.x;
    const int lane = tid & 63, wv = tid >> 6;
    if (tid == 0) carry = 0;
    __syncthreads();
    for (int base = 0; base < N_NODES; base += 1024) {
        const int i = base + tid;
        const int v = (i < N_NODES) ? cnt[i] : 0;
        int x = v;
        #pragma unroll
        for (int off = 1; off < 64; off <<= 1) {
            int y = __shfl_up(x, off);
            if (lane >= off) x += y;
        }
        if (lane == 63) wsum[wv] = x;
        __syncthreads();
        if (tid < 16) {
            int s = wsum[tid];
            #pragma unroll
            for (int off = 1; off < 16; off <<= 1) {
                int y = __shfl_up(s, off);
                if (tid >= off) s += y;
            }
            wsum[tid] = s;
        }
        __syncthreads();
        const int waveoff = (wv == 0) ? 0 : wsum[wv - 1];
        const int excl = carry + waveoff + (x - v);
        const int tot  = carry + wsum[15];
        __syncthreads();
        if (i < N_NODES) cnt[i] = excl;
        if (tid == 0) carry = tot;
        __syncthreads();
    }
}

__global__ __launch_bounds__(256) void k_scatter(
    const int* __restrict__ srcA, const int* __restrict__ dstA,
    int* __restrict__ rowptr, int* __restrict__ sorted_src)
{
    const int e = blockIdx.x * 256 + threadIdx.x;
    if (e >= E_EDGES) return;
    const int d = dstA[e];
    const int p = atomicAdd(&rowptr[d], 1);
    sorted_src[p] = srcA[e];
}

// ---------------------------------------------------------------------------
// Layer 1 node pre-pass (register-tiled): xw1b = bf16(x @ W1) [N,128];
// logit halves al_s/al_d [N,2]. Block = 32 nodes x 128 cols; thread = 4x4.
// ---------------------------------------------------------------------------
__global__ __launch_bounds__(256) void k_node1(
    const float* __restrict__ x, const float* __restrict__ W1,
    const float* __restrict__ a_src, const float* __restrict__ a_dst,
    unsigned short* __restrict__ xw1b,
    float* __restrict__ al_s, float* __restrict__ al_d)
{
    __shared__ float sW[IN_CH * 132];   // rows padded to 132 (16B-aligned float4)
    __shared__ float sx[32 * 35];       // stride 35: conflict-free scalar reads
    __shared__ float sas[128], sad[128];
    const int tid = threadIdx.x;
    for (int i = tid; i < IN_CH * 128; i += 256) {
        int k = i >> 7, c = i & 127;
        sW[k * 132 + c] = W1[i];
    }
    if (tid < 128) { sas[tid] = a_src[tid]; sad[tid] = a_dst[tid]; }
    const int n0 = blockIdx.x * 32;
    for (int i = tid; i < 32 * IN_CH; i += 256) {
        int n = i / IN_CH, c = i - n * IN_CH;
        sx[n * 35 + c] = (n0 + n < N_NODES) ? x[n0 * IN_CH + i] : 0.f;
    }
    __syncthreads();

    const int tc = tid & 31, tn = tid >> 5;     // 32 col-groups x 8 node-groups
    float acc[4][4] = {{0.f}};
    for (int k = 0; k < IN_CH; ++k) {
        const float4 wv = *reinterpret_cast<const float4*>(&sW[k * 132 + 4 * tc]);
        #pragma unroll
        for (int j = 0; j < 4; ++j) {
            const float hj = sx[(4 * tn + j) * 35 + k];
            acc[j][0] += hj * wv.x; acc[j][1] += hj * wv.y;
            acc[j][2] += hj * wv.z; acc[j][3] += hj * wv.w;
        }
    }
    #pragma unroll
    for (int j = 0; j < 4; ++j) {
        const int node = n0 + 4 * tn + j;
        float ps = 0.f, pd = 0.f;
        #pragma unroll
        for (int c = 0; c < 4; ++c) {
            ps += acc[j][c] * sas[4 * tc + c];
            pd += acc[j][c] * sad[4 * tc + c];
        }
        #pragma unroll
        for (int off = 1; off < 16; off <<= 1) {   // reduce within 16-lane head group
            ps += __shfl_xor(ps, off);
            pd += __shfl_xor(pd, off);
        }
        if (node < N_NODES) {
            if ((tc & 15) == 0) {
                int h = tc >> 4;
                al_s[node * 2 + h] = ps;
                al_d[node * 2 + h] = pd;
            }
            ushort4 u;
            u.x = f2bf(acc[j][0]); u.y = f2bf(acc[j][1]);
            u.z = f2bf(acc[j][2]); u.w = f2bf(acc[j][3]);
            *reinterpret_cast<ushort4*>(&xw1b[node * 128 + 4 * tc]) = u;
        }
    }
}

// ---------------------------------------------------------------------------
// Layer 1 gather: one wave per (node, head). Batch 64 edges: stage
// (row_offset, weight) in LDS, broadcast-read b64, 4-way unrolled MLP.
// Fused finalize: h = relu(acc/den + b1).
// ---------------------------------------------------------------------------
__global__ __launch_bounds__(256) void k_gather1(
    const int* __restrict__ rowptr, const int* __restrict__ sorted_src,
    const unsigned short* __restrict__ xw1b,
    const float* __restrict__ al_s, const float* __restrict__ al_d,
    const float* __restrict__ b1, float* __restrict__ hbuf)
{
    __shared__ float2 ebuf[4][64];
    const int wave = threadIdx.x >> 6;
    const int lane = threadIdx.x & 63;
    const int wid  = (blockIdx.x * 256 + threadIdx.x) >> 6;
    const int node = wid >> 1, h = wid & 1;
    if (node >= N_NODES) return;
    const int beg = (node == 0) ? 0 : rowptr[node - 1];
    const int end = rowptr[node];
    const int col = h * 64 + lane;

    const float ald = al_d[node * 2 + h];
    const float w0 = lrelu_exp(al_s[node * 2 + h] + ald);
    float acc0 = w0 * bf2f(xw1b[node * 128 + col]);
    float acc1 = 0.f, acc2 = 0.f, acc3 = 0.f;
    float den = w0;

    for (int base = beg; base < end; base += 64) {
        const int rem = end - base;
        const int m = rem < 64 ? rem : 64;
        float wv = 0.f;
        if (lane < m) {
            const int s = sorted_src[base + lane];
            wv = lrelu_exp(al_s[s * 2 + h] + ald);
            ebuf[wave][lane] = make_float2(__int_as_float(s << 7), wv);
        }
        int j = 0;
        for (; j + 4 <= m; j += 4) {
            const float2 p0 = ebuf[wave][j + 0];
            const float2 p1 = ebuf[wave][j + 1];
            const float2 p2 = ebuf[wave][j + 2];
            const float2 p3 = ebuf[wave][j + 3];
            acc0 += p0.y * bf2f(xw1b[__float_as_int(p0.x) + col]);
            acc1 += p1.y * bf2f(xw1b[__float_as_int(p1.x) + col]);
            acc2 += p2.y * bf2f(xw1b[__float_as_int(p2.x) + col]);
            acc3 += p3.y * bf2f(xw1b[__float_as_int(p3.x) + col]);
        }
        for (; j < m; ++j) {
            const float2 p = ebuf[wave][j];
            acc0 += p.y * bf2f(xw1b[__float_as_int(p.x) + col]);
        }
        float t = wv;
        #pragma unroll
        for (int off = 32; off; off >>= 1) t += __shfl_xor(t, off);
        den += t;
    }
    const float v = (acc0 + acc1 + acc2 + acc3) / den + b1[col];
    hbuf[node * 128 + col] = v > 0.f ? v : 0.f;
}

// ---------------------------------------------------------------------------
// Layer 2 node pre-pass (register-tiled): xw2 = h @ W2 [N,64] fp32.
// Block = 64 nodes x 64 cols; thread = 4x4.
// ---------------------------------------------------------------------------
__global__ __launch_bounds__(256) void k_node2(
    const float* __restrict__ hbuf, const float* __restrict__ W2,
    const float* __restrict__ a_src, const float* __restrict__ a_dst,
    float* __restrict__ xw2, float* __restrict__ al_s, float* __restrict__ al_d)
{
    __shared__ float sW[128 * 64];      // natural [k][col], rows 256B (float4 ok)
    __shared__ float sh[64 * 129];      // stride 129: conflict-free scalar reads
    __shared__ float sas[64], sad[64];
    const int tid = threadIdx.x;
    for (int i = tid; i < 128 * 64; i += 256) sW[i] = W2[i];
    if (tid < 64) { sas[tid] = a_src[tid]; sad[tid] = a_dst[tid]; }
    const int n0 = blockIdx.x * 64;
    for (int i = tid; i < 64 * 128; i += 256) {
        int n = i >> 7, c = i & 127;
        sh[n * 129 + c] = (n0 + n < N_NODES) ? hbuf[(long)(n0 + n) * 128 + c] : 0.f;
    }
    __syncthreads();

    const int tc = tid & 15, tn = tid >> 4;     // 16 col-groups x 16 node-groups
    float acc[4][4] = {{0.f}};
    for (int k = 0; k < 128; ++k) {
        const float4 wv = *reinterpret_cast<const float4*>(&sW[k * 64 + 4 * tc]);
        #pragma unroll
        for (int j = 0; j < 4; ++j) {
            const float hj = sh[(4 * tn + j) * 129 + k];
            acc[j][0] += hj * wv.x; acc[j][1] += hj * wv.y;
            acc[j][2] += hj * wv.z; acc[j][3] += hj * wv.w;
        }
    }
    #pragma unroll
    for (int j = 0; j < 4; ++j) {
        const int node = n0 + 4 * tn + j;
        float ps = 0.f, pd = 0.f;
        #pragma unroll
        for (int c = 0; c < 4; ++c) {
            ps += acc[j][c] * sas[4 * tc + c];
            pd += acc[j][c] * sad[4 * tc + c];
        }
        #pragma unroll
        for (int off = 1; off < 16; off <<= 1) {
            ps += __shfl_xor(ps, off);
            pd += __shfl_xor(pd, off);
        }
        if (node < N_NODES) {
            if (tc == 0) { al_s[node] = ps; al_d[node] = pd; }
            *reinterpret_cast<float4*>(&xw2[node * 64 + 4 * tc]) =
                make_float4(acc[j][0], acc[j][1], acc[j][2], acc[j][3]);
        }
    }
}

// ---------------------------------------------------------------------------
// Layer 2 gather: one wave per node, fp32 rows, same LDS-broadcast scheme.
// Fused finalize: out = acc/den + b2.
// ---------------------------------------------------------------------------
__global__ __launch_bounds__(256) void k_gather2(
    const int* __restrict__ rowptr, const int* __restrict__ sorted_src,
    const float* __restrict__ xw2,
    const float* __restrict__ al_s, const float* __restrict__ al_d,
    const float* __restrict__ b2, float* __restrict__ out)
{
    __shared__ float2 ebuf[4][64];
    const int wave = threadIdx.x >> 6;
    const int lane = threadIdx.x & 63;
    const int node = (blockIdx.x * 256 + threadIdx.x) >> 6;
    if (node >= N_NODES) return;
    const int beg = (node == 0) ? 0 : rowptr[node - 1];
    const int end = rowptr[node];

    const float ald = al_d[node];
    const float w0 = lrelu_exp(al_s[node] + ald);
    float acc0 = w0 * xw2[node * 64 + lane];
    float acc1 = 0.f, acc2 = 0.f, acc3 = 0.f;
    float den = w0;

    for (int base = beg; base < end; base += 64) {
        const int rem = end - base;
        const int m = rem < 64 ? rem : 64;
        float wv = 0.f;
        if (lane < m) {
            const int s = sorted_src[base + lane];
            wv = lrelu_exp(al_s[s] + ald);
            ebuf[wave][lane] = make_float2(__int_as_float(s << 6), wv);
        }
        int j = 0;
        for (; j + 4 <= m; j += 4) {
            const float2 p0 = ebuf[wave][j + 0];
            const float2 p1 = ebuf[wave][j + 1];
            const float2 p2 = ebuf[wave][j + 2];
            const float2 p3 = ebuf[wave][j + 3];
            acc0 += p0.y * xw2[__float_as_int(p0.x) + lane];
            acc1 += p1.y * xw2[__float_as_int(p1.x) + lane];
            acc2 += p2.y * xw2[__float_as_int(p2.x) + lane];
            acc3 += p3.y * xw2[__float_as_int(p3.x) + lane];
        }
        for (; j < m; ++j) {
            const float2 p = ebuf[wave][j];
            acc0 += p.y * xw2[__float_as_int(p.x) + lane];
        }
        float t = wv;
        #pragma unroll
        for (int off = 32; off; off >>= 1) t += __shfl_xor(t, off);
        den += t;
    }
    out[node * 64 + lane] = (acc0 + acc1 + acc2 + acc3) / den + b2[lane];
}

extern "C" void kernel_launch(void* const* d_in, const int* in_sizes, int n_in,
                              void* d_out, int out_size, void* d_ws, size_t ws_size,
                              hipStream_t stream)
{
    const float* x   = (const float*)d_in[0];
    const int*   ei  = (const int*)d_in[1];
    const float* W1  = (const float*)d_in[2];
    const float* as1 = (const float*)d_in[3];
    const float* ad1 = (const float*)d_in[4];
    const float* b1  = (const float*)d_in[5];
    const float* W2  = (const float*)d_in[6];
    const float* as2 = (const float*)d_in[7];
    const float* ad2 = (const float*)d_in[8];
    const float* b2  = (const float*)d_in[9];
    float* out = (float*)d_out;

    const int* srcA = ei;
    const int* dstA = ei + E_EDGES;

    // Workspace layout (bytes). Total 59,004,800 B (same budget as R2).
    char* ws = (char*)d_ws;
    int*   rowptr     = (int*)(ws);                        // (N+1) ints
    int*   sorted_src = (int*)(ws + 204800);               // 6.4 MB
    float* al_s1      = (float*)(ws + 6604800);            // 400 KB
    float* al_d1      = (float*)(ws + 7004800);            // 400 KB
    float* al_s2      = (float*)(ws + 7404800);            // 200 KB
    float* al_d2      = (float*)(ws + 7604800);            // 200 KB
    unsigned short* xw1b = (unsigned short*)(ws + 7804800); // 12.8 MB bf16
    float* hbuf       = (float*)(ws + 20604800);           // 25.6 MB fp32
    float* xw2        = (float*)(ws + 46204800);           // 12.8 MB fp32

    hipMemsetAsync(rowptr, 0, (N_NODES + 1) * sizeof(int), stream);
    hipLaunchKernelGGL(k_hist, dim3((E_EDGES + 255) / 256), dim3(256), 0, stream,
                       dstA, rowptr);
    hipLaunchKernelGGL(k_scan, dim3(1), dim3(1024), 0, stream, rowptr);
    hipLaunchKernelGGL(k_scatter, dim3((E_EDGES + 255) / 256), dim3(256), 0, stream,
                       srcA, dstA, rowptr, sorted_src);

    hipLaunchKernelGGL(k_node1, dim3((N_NODES + 31) / 32), dim3(256), 0, stream,
                       x, W1, as1, ad1, xw1b, al_s1, al_d1);
    hipLaunchKernelGGL(k_gather1, dim3((N_NODES * 2 + 3) / 4), dim3(256), 0, stream,
                       rowptr, sorted_src, xw1b, al_s1, al_d1, b1, hbuf);
    hipLaunchKernelGGL(k_node2, dim3((N_NODES + 63) / 64), dim3(256), 0, stream,
                       hbuf, W2, as2, ad2, xw2, al_s2, al_d2);
    hipLaunchKernelGGL(k_gather2, dim3((N_NODES + 3) / 4), dim3(256), 0, stream,
                       rowptr, sorted_src, xw2, al_s2, al_d2, b2, out);
}

// Round 4
// 313.943 us; speedup vs baseline: 14.0065x; 1.6776x over previous
//
#include <hip/hip_runtime.h>
#include <math.h>

#define N_NODES 50000
#define E_EDGES 1600000
#define IN_CH   34
#define NEG     0.2f
#define NB      196          // coarse buckets: dst>>8, 49999>>8 = 195

static __device__ __forceinline__ unsigned short f2bf(float f) {
    unsigned int u = __float_as_uint(f);
    u += 0x7fffu + ((u >> 16) & 1u);          // round-to-nearest-even
    return (unsigned short)(u >> 16);
}
static __device__ __forceinline__ float bf2f(unsigned short s) {
    return __uint_as_float(((unsigned int)s) << 16);
}
static __device__ __forceinline__ float bflo(unsigned int u) {
    return __uint_as_float(u << 16);
}
static __device__ __forceinline__ float bfhi(unsigned int u) {
    return __uint_as_float(u & 0xffff0000u);
}
static __device__ __forceinline__ float lrelu_exp(float e) {
    return expf(e > 0.f ? e : NEG * e);
}

// 256-thread block exclusive scan. wsum = int[4] LDS scratch.
static __device__ __forceinline__ int scan256_excl(int v, int* wsum) {
    const int lane = threadIdx.x & 63, wv = threadIdx.x >> 6;
    int x = v;
    #pragma unroll
    for (int off = 1; off < 64; off <<= 1) {
        int y = __shfl_up(x, off);
        if (lane >= off) x += y;
    }
    if (lane == 63) wsum[wv] = x;
    __syncthreads();
    if (threadIdx.x < 4) {
        int s = wsum[threadIdx.x];
        #pragma unroll
        for (int off = 1; off < 4; off <<= 1) {
            int y = __shfl_up(s, off);
            if ((int)threadIdx.x >= off) s += y;
        }
        wsum[threadIdx.x] = s;
    }
    __syncthreads();
    const int woff = wv ? wsum[wv - 1] : 0;
    return woff + x - v;
}

// ---------------------------------------------------------------------------
// Sort phase A0: coarse bucket histogram (LDS pre-reduced).
// ---------------------------------------------------------------------------
__global__ __launch_bounds__(256) void k_bhist(
    const int* __restrict__ dstA, int* __restrict__ bhist)
{
    __shared__ int c[256];
    const int tid = threadIdx.x;
    c[tid] = 0;
    __syncthreads();
    const int base = blockIdx.x * 4096;
    #pragma unroll
    for (int i = 0; i < 16; ++i) {
        const int e = base + i * 256 + tid;
        if (e < E_EDGES) atomicAdd(&c[dstA[e] >> 8], 1);
    }
    __syncthreads();
    if (tid < NB && c[tid]) atomicAdd(&bhist[tid], c[tid]);
}

// A1: scan NB bucket totals -> gbase[NB+1]; init gcur cursors.
__global__ __launch_bounds__(256) void k_bscan(
    const int* __restrict__ bhist, int* __restrict__ gbase, int* __restrict__ gcur)
{
    __shared__ int wsum[4];
    const int tid = threadIdx.x;
    const int v = (tid < NB) ? bhist[tid] : 0;
    const int excl = scan256_excl(v, wsum);
    if (tid < NB) { gbase[tid] = excl; gcur[tid] = excl; }
    if (tid == NB - 1) gbase[NB] = excl + v;
}

// A2: bin edges into bucket-contiguous `binned` ((dst<<16)|src packed words).
__global__ __launch_bounds__(256) void k_bin(
    const int* __restrict__ srcA, const int* __restrict__ dstA,
    int* __restrict__ gcur, unsigned int* __restrict__ binned)
{
    __shared__ unsigned int ebuf[8192];   // 32 KB
    __shared__ int cnt[256], loff[256], lcur[256], cur[256];
    __shared__ int wsum[4];
    const int tid = threadIdx.x;
    cnt[tid] = 0;
    __syncthreads();
    const int base = blockIdx.x * 8192;
    #pragma unroll
    for (int i = 0; i < 32; ++i) {
        const int e = base + i * 256 + tid;
        if (e < E_EDGES) atomicAdd(&cnt[dstA[e] >> 8], 1);
    }
    __syncthreads();
    const int v = cnt[tid];
    const int excl = scan256_excl(v, wsum);
    loff[tid] = excl;
    lcur[tid] = excl;
    cur[tid] = (tid < NB && v > 0) ? atomicAdd(&gcur[tid], v) : 0;
    __syncthreads();
    #pragma unroll
    for (int i = 0; i < 32; ++i) {
        const int e = base + i * 256 + tid;
        if (e < E_EDGES) {
            const int d = dstA[e], s = srcA[e];
            const int p = atomicAdd(&lcur[d >> 8], 1);
            ebuf[p] = ((unsigned int)d << 16) | (unsigned int)s;
        }
    }
    __syncthreads();
    const int mE = min(8192, E_EDGES - base);
    #pragma unroll
    for (int i = 0; i < 32; ++i) {
        const int p = i * 256 + tid;
        if (p < mE) {
            const unsigned int u = ebuf[p];
            const int b = (int)(u >> 24);
            binned[cur[b] + (p - loff[b])] = u;
        }
    }
}

// B: per-bucket fine sort into sorted_src + rowptr (end pointers).
__global__ __launch_bounds__(256) void k_fine(
    const int* __restrict__ gbase, const unsigned int* __restrict__ binned,
    int* __restrict__ rowptr, int* __restrict__ sorted_src)
{
    __shared__ int cnt[256], lcur[256];
    __shared__ int wsum[4];
    const int tid = threadIdx.x;
    const int b = blockIdx.x;
    const int beg = gbase[b], endb = gbase[b + 1];
    cnt[tid] = 0;
    __syncthreads();
    for (int p = beg + tid; p < endb; p += 256)
        atomicAdd(&cnt[(binned[p] >> 16) & 255], 1);
    __syncthreads();
    const int v = cnt[tid];
    const int excl = scan256_excl(v, wsum);
    const int node = b * 256 + tid;
    if (node < N_NODES) rowptr[node] = beg + excl + v;
    lcur[tid] = excl;
    __syncthreads();
    for (int p = beg + tid; p < endb; p += 256) {
        const unsigned int u = binned[p];
        const int ln = (int)((u >> 16) & 255);
        const int q = atomicAdd(&lcur[ln], 1);
        sorted_src[beg + q] = (int)(u & 0xffffu);
    }
}

// ---------------------------------------------------------------------------
// Layer 1 node pre-pass (register-tiled): xw1b = bf16(x @ W1) [N,128];
// logit halves al_s/al_d [N,2]. Block = 32 nodes x 128 cols; thread = 4x4.
// ---------------------------------------------------------------------------
__global__ __launch_bounds__(256) void k_node1(
    const float* __restrict__ x, const float* __restrict__ W1,
    const float* __restrict__ a_src, const float* __restrict__ a_dst,
    unsigned short* __restrict__ xw1b,
    float* __restrict__ al_s, float* __restrict__ al_d)
{
    __shared__ float sW[IN_CH * 132];
    __shared__ float sx[32 * 35];
    __shared__ float sas[128], sad[128];
    const int tid = threadIdx.x;
    for (int i = tid; i < IN_CH * 128; i += 256) {
        int k = i >> 7, c = i & 127;
        sW[k * 132 + c] = W1[i];
    }
    if (tid < 128) { sas[tid] = a_src[tid]; sad[tid] = a_dst[tid]; }
    const int n0 = blockIdx.x * 32;
    for (int i = tid; i < 32 * IN_CH; i += 256) {
        int n = i / IN_CH, c = i - n * IN_CH;
        sx[n * 35 + c] = (n0 + n < N_NODES) ? x[n0 * IN_CH + i] : 0.f;
    }
    __syncthreads();

    const int tc = tid & 31, tn = tid >> 5;
    float acc[4][4] = {{0.f}};
    for (int k = 0; k < IN_CH; ++k) {
        const float4 wv = *reinterpret_cast<const float4*>(&sW[k * 132 + 4 * tc]);
        #pragma unroll
        for (int j = 0; j < 4; ++j) {
            const float hj = sx[(4 * tn + j) * 35 + k];
            acc[j][0] += hj * wv.x; acc[j][1] += hj * wv.y;
            acc[j][2] += hj * wv.z; acc[j][3] += hj * wv.w;
        }
    }
    #pragma unroll
    for (int j = 0; j < 4; ++j) {
        const int node = n0 + 4 * tn + j;
        float ps = 0.f, pd = 0.f;
        #pragma unroll
        for (int c = 0; c < 4; ++c) {
            ps += acc[j][c] * sas[4 * tc + c];
            pd += acc[j][c] * sad[4 * tc + c];
        }
        #pragma unroll
        for (int off = 1; off < 16; off <<= 1) {
            ps += __shfl_xor(ps, off);
            pd += __shfl_xor(pd, off);
        }
        if (node < N_NODES) {
            if ((tc & 15) == 0) {
                int h = tc >> 4;
                al_s[node * 2 + h] = ps;
                al_d[node * 2 + h] = pd;
            }
            ushort4 u;
            u.x = f2bf(acc[j][0]); u.y = f2bf(acc[j][1]);
            u.z = f2bf(acc[j][2]); u.w = f2bf(acc[j][3]);
            *reinterpret_cast<ushort4*>(&xw1b[node * 128 + 4 * tc]) = u;
        }
    }
}

// ---------------------------------------------------------------------------
// Layer 1 gather, combined heads: one wave per node. Lane l covers cols
// 2l,2l+1 (head l>>5) via one uint (2 bf16) load. 8-deep unrolled MLP.
// Fused finalize: h = relu(acc/den + b1).
// ---------------------------------------------------------------------------
__global__ __launch_bounds__(256) void k_gather1(
    const int* __restrict__ rowptr, const int* __restrict__ sorted_src,
    const unsigned int* __restrict__ xw1u,    // xw1b as uints, 64/row
    const float* __restrict__ al_s, const float* __restrict__ al_d,
    const float* __restrict__ b1, float* __restrict__ hbuf)
{
    __shared__ float4 ebuf[4][64];
    const int wave = threadIdx.x >> 6;
    const int lane = threadIdx.x & 63;
    const int node = (blockIdx.x * 256 + threadIdx.x) >> 6;
    if (node >= N_NODES) return;
    const int beg = (node == 0) ? 0 : rowptr[node - 1];
    const int end = rowptr[node];

    const float2 ald = *reinterpret_cast<const float2*>(&al_d[node * 2]);
    const float2 als0 = *reinterpret_cast<const float2*>(&al_s[node * 2]);
    const float w0h0 = lrelu_exp(als0.x + ald.x);
    const float w0h1 = lrelu_exp(als0.y + ald.y);
    const float wself = (lane < 32) ? w0h0 : w0h1;
    {
    }
    const unsigned int su = xw1u[node * 64 + lane];
    float accL0 = wself * bflo(su), accH0 = wself * bfhi(su);
    float accL1 = 0.f, accH1 = 0.f, accL2 = 0.f, accH2 = 0.f, accL3 = 0.f, accH3 = 0.f;
    float dv0 = 0.f, dv1 = 0.f;
    float4* eb = ebuf[wave];

    for (int base = beg; base < end; base += 64) {
        const int rem = end - base;
        const int m = rem < 64 ? rem : 64;
        if (lane < m) {
            const int s = sorted_src[base + lane];
            const float2 als = *reinterpret_cast<const float2*>(&al_s[s * 2]);
            const float w0 = lrelu_exp(als.x + ald.x);
            const float w1 = lrelu_exp(als.y + ald.y);
            dv0 += w0; dv1 += w1;
            eb[lane] = make_float4(__int_as_float(s << 6), w0, w1, 0.f);
        }
        int j = 0;
        for (; j + 8 <= m; j += 8) {
            const float4 p0 = eb[j + 0], p1 = eb[j + 1], p2 = eb[j + 2], p3 = eb[j + 3];
            const float4 p4 = eb[j + 4], p5 = eb[j + 5], p6 = eb[j + 6], p7 = eb[j + 7];
            const unsigned int v0 = xw1u[__float_as_int(p0.x) + lane];
            const unsigned int v1 = xw1u[__float_as_int(p1.x) + lane];
            const unsigned int v2 = xw1u[__float_as_int(p2.x) + lane];
            const unsigned int v3 = xw1u[__float_as_int(p3.x) + lane];
            const unsigned int v4 = xw1u[__float_as_int(p4.x) + lane];
            const unsigned int v5 = xw1u[__float_as_int(p5.x) + lane];
            const unsigned int v6 = xw1u[__float_as_int(p6.x) + lane];
            const unsigned int v7 = xw1u[__float_as_int(p7.x) + lane];
            const float w0 = (lane < 32) ? p0.y : p0.z;
            const float w1 = (lane < 32) ? p1.y : p1.z;
            const float w2 = (lane < 32) ? p2.y : p2.z;
            const float w3 = (lane < 32) ? p3.y : p3.z;
            const float w4 = (lane < 32) ? p4.y : p4.z;
            const float w5 = (lane < 32) ? p5.y : p5.z;
            const float w6 = (lane < 32) ? p6.y : p6.z;
            const float w7 = (lane < 32) ? p7.y : p7.z;
            accL0 += w0 * bflo(v0); accH0 += w0 * bfhi(v0);
            accL1 += w1 * bflo(v1); accH1 += w1 * bfhi(v1);
            accL2 += w2 * bflo(v2); accH2 += w2 * bfhi(v2);
            accL3 += w3 * bflo(v3); accH3 += w3 * bfhi(v3);
            accL0 += w4 * bflo(v4); accH0 += w4 * bfhi(v4);
            accL1 += w5 * bflo(v5); accH1 += w5 * bfhi(v5);
            accL2 += w6 * bflo(v6); accH2 += w6 * bfhi(v6);
            accL3 += w7 * bflo(v7); accH3 += w7 * bfhi(v7);
        }
        for (; j < m; ++j) {
            const float4 p = eb[j];
            const unsigned int v = xw1u[__float_as_int(p.x) + lane];
            const float w = (lane < 32) ? p.y : p.z;
            accL0 += w * bflo(v); accH0 += w * bfhi(v);
        }
    }
    #pragma unroll
    for (int off = 32; off; off >>= 1) {
        dv0 += __shfl_xor(dv0, off);
        dv1 += __shfl_xor(dv1, off);
    }
    const float den = ((lane < 32) ? (dv0 + w0h0) : (dv1 + w0h1));
    const float2 bv = *reinterpret_cast<const float2*>(&b1[2 * lane]);
    float oL = (accL0 + accL1 + accL2 + accL3) / den + bv.x;
    float oH = (accH0 + accH1 + accH2 + accH3) / den + bv.y;
    oL = oL > 0.f ? oL : 0.f;
    oH = oH > 0.f ? oH : 0.f;
    *reinterpret_cast<float2*>(&hbuf[node * 128 + 2 * lane]) = make_float2(oL, oH);
}

// ---------------------------------------------------------------------------
// Layer 2 node pre-pass (register-tiled): xw2b = bf16(h @ W2) [N,64].
// ---------------------------------------------------------------------------
__global__ __launch_bounds__(256) void k_node2(
    const float* __restrict__ hbuf, const float* __restrict__ W2,
    const float* __restrict__ a_src, const float* __restrict__ a_dst,
    unsigned short* __restrict__ xw2b, float* __restrict__ al_s, float* __restrict__ al_d)
{
    __shared__ float sW[128 * 64];
    __shared__ float sh[64 * 129];
    __shared__ float sas[64], sad[64];
    const int tid = threadIdx.x;
    for (int i = tid; i < 128 * 64; i += 256) sW[i] = W2[i];
    if (tid < 64) { sas[tid] = a_src[tid]; sad[tid] = a_dst[tid]; }
    const int n0 = blockIdx.x * 64;
    for (int i = tid; i < 64 * 128; i += 256) {
        int n = i >> 7, c = i & 127;
        sh[n * 129 + c] = (n0 + n < N_NODES) ? hbuf[(long)(n0 + n) * 128 + c] : 0.f;
    }
    __syncthreads();

    const int tc = tid & 15, tn = tid >> 4;
    float acc[4][4] = {{0.f}};
    for (int k = 0; k < 128; ++k) {
        const float4 wv = *reinterpret_cast<const float4*>(&sW[k * 64 + 4 * tc]);
        #pragma unroll
        for (int j = 0; j < 4; ++j) {
            const float hj = sh[(4 * tn + j) * 129 + k];
            acc[j][0] += hj * wv.x; acc[j][1] += hj * wv.y;
            acc[j][2] += hj * wv.z; acc[j][3] += hj * wv.w;
        }
    }
    #pragma unroll
    for (int j = 0; j < 4; ++j) {
        const int node = n0 + 4 * tn + j;
        float ps = 0.f, pd = 0.f;
        #pragma unroll
        for (int c = 0; c < 4; ++c) {
            ps += acc[j][c] * sas[4 * tc + c];
            pd += acc[j][c] * sad[4 * tc + c];
        }
        #pragma unroll
        for (int off = 1; off < 16; off <<= 1) {
            ps += __shfl_xor(ps, off);
            pd += __shfl_xor(pd, off);
        }
        if (node < N_NODES) {
            if (tc == 0) { al_s[node] = ps; al_d[node] = pd; }
            ushort4 u;
            u.x = f2bf(acc[j][0]); u.y = f2bf(acc[j][1]);
            u.z = f2bf(acc[j][2]); u.w = f2bf(acc[j][3]);
            *reinterpret_cast<ushort4*>(&xw2b[node * 64 + 4 * tc]) = u;
        }
    }
}

// ---------------------------------------------------------------------------
// Layer 2 gather: one wave per node, bf16 rows, 8-deep unroll.
// Fused finalize: out = acc/den + b2.
// ---------------------------------------------------------------------------
__global__ __launch_bounds__(256) void k_gather2(
    const int* __restrict__ rowptr, const int* __restrict__ sorted_src,
    const unsigned short* __restrict__ xw2b,
    const float* __restrict__ al_s, const float* __restrict__ al_d,
    const float* __restrict__ b2, float* __restrict__ out)
{
    __shared__ float2 ebuf[4][64];
    const int wave = threadIdx.x >> 6;
    const int lane = threadIdx.x & 63;
    const int node = (blockIdx.x * 256 + threadIdx.x) >> 6;
    if (node >= N_NODES) return;
    const int beg = (node == 0) ? 0 : rowptr[node - 1];
    const int end = rowptr[node];

    const float ald = al_d[node];
    const float w0 = lrelu_exp(al_s[node] + ald);
    float acc0 = w0 * bf2f(xw2b[node * 64 + lane]);
    float acc1 = 0.f, acc2 = 0.f, acc3 = 0.f;
    float den = w0;
    float2* eb = ebuf[wave];

    for (int base = beg; base < end; base += 64) {
        const int rem = end - base;
        const int m = rem < 64 ? rem : 64;
        float wv = 0.f;
        if (lane < m) {
            const int s = sorted_src[base + lane];
            wv = lrelu_exp(al_s[s] + ald);
            eb[lane] = make_float2(__int_as_float(s << 6), wv);
        }
        int j = 0;
        for (; j + 8 <= m; j += 8) {
            const float2 p0 = eb[j + 0], p1 = eb[j + 1], p2 = eb[j + 2], p3 = eb[j + 3];
            const float2 p4 = eb[j + 4], p5 = eb[j + 5], p6 = eb[j + 6], p7 = eb[j + 7];
            const unsigned short v0 = xw2b[__float_as_int(p0.x) + lane];
            const unsigned short v1 = xw2b[__float_as_int(p1.x) + lane];
            const unsigned short v2 = xw2b[__float_as_int(p2.x) + lane];
            const unsigned short v3 = xw2b[__float_as_int(p3.x) + lane];
            const unsigned short v4 = xw2b[__float_as_int(p4.x) + lane];
            const unsigned short v5 = xw2b[__float_as_int(p5.x) + lane];
            const unsigned short v6 = xw2b[__float_as_int(p6.x) + lane];
            const unsigned short v7 = xw2b[__float_as_int(p7.x) + lane];
            acc0 += p0.y * bf2f(v0); acc1 += p1.y * bf2f(v1);
            acc2 += p2.y * bf2f(v2); acc3 += p3.y * bf2f(v3);
            acc0 += p4.y * bf2f(v4); acc1 += p5.y * bf2f(v5);
            acc2 += p6.y * bf2f(v6); acc3 += p7.y * bf2f(v7);
        }
        for (; j < m; ++j) {
            const float2 p = eb[j];
            acc0 += p.y * bf2f(xw2b[__float_as_int(p.x) + lane]);
        }
        float t = wv;
        #pragma unroll
        for (int off = 32; off; off >>= 1) t += __shfl_xor(t, off);
        den += t;
    }
    out[node * 64 + lane] = (acc0 + acc1 + acc2 + acc3) / den + b2[lane];
}

extern "C" void kernel_launch(void* const* d_in, const int* in_sizes, int n_in,
                              void* d_out, int out_size, void* d_ws, size_t ws_size,
                              hipStream_t stream)
{
    const float* x   = (const float*)d_in[0];
    const int*   ei  = (const int*)d_in[1];
    const float* W1  = (const float*)d_in[2];
    const float* as1 = (const float*)d_in[3];
    const float* ad1 = (const float*)d_in[4];
    const float* b1  = (const float*)d_in[5];
    const float* W2  = (const float*)d_in[6];
    const float* as2 = (const float*)d_in[7];
    const float* ad2 = (const float*)d_in[8];
    const float* b2  = (const float*)d_in[9];
    float* out = (float*)d_out;

    const int* srcA = ei;
    const int* dstA = ei + E_EDGES;

    // Workspace layout (bytes). Total 52,610,944 B.
    char* ws = (char*)d_ws;
    int*   rowptr     = (int*)(ws);                          // 200,000 B (pad 204,800)
    int*   sorted_src = (int*)(ws + 204800);                 // 6.4 MB
    int*   bhist      = (int*)(ws + 6604800);                // 1 KB (pad 2 KB)
    int*   gbase      = (int*)(ws + 6606848);                // (NB+1) ints
    int*   gcur       = (int*)(ws + 6608896);                // NB ints
    float* al_s1      = (float*)(ws + 6610944);              // 400 KB
    float* al_d1      = (float*)(ws + 7010944);              // 400 KB
    float* al_s2      = (float*)(ws + 7410944);              // 200 KB
    float* al_d2      = (float*)(ws + 7610944);              // 200 KB
    unsigned short* xw1b = (unsigned short*)(ws + 7810944);  // 12.8 MB bf16
    float* hbuf       = (float*)(ws + 20610944);             // 25.6 MB fp32
    unsigned int* binned = (unsigned int*)hbuf;              // alias: dead before gather1
    unsigned short* xw2b = (unsigned short*)(ws + 46210944); // 6.4 MB bf16

    hipMemsetAsync(bhist, 0, 256 * sizeof(int), stream);
    hipLaunchKernelGGL(k_bhist, dim3((E_EDGES + 4095) / 4096), dim3(256), 0, stream,
                       dstA, bhist);
    hipLaunchKernelGGL(k_bscan, dim3(1), dim3(256), 0, stream, bhist, gbase, gcur);
    hipLaunchKernelGGL(k_bin, dim3((E_EDGES + 8191) / 8192), dim3(256), 0, stream,
                       srcA, dstA, gcur, binned);
    hipLaunchKernelGGL(k_fine, dim3(NB), dim3(256), 0, stream,
                       gbase, binned, rowptr, sorted_src);

    hipLaunchKernelGGL(k_node1, dim3((N_NODES + 31) / 32), dim3(256), 0, stream,
                       x, W1, as1, ad1, xw1b, al_s1, al_d1);
    hipLaunchKernelGGL(k_gather1, dim3((N_NODES + 3) / 4), dim3(256), 0, stream,
                       rowptr, sorted_src, (const unsigned int*)xw1b,
                       al_s1, al_d1, b1, hbuf);
    hipLaunchKernelGGL(k_node2, dim3((N_NODES + 63) / 64), dim3(256), 0, stream,
                       hbuf, W2, as2, ad2, xw2b, al_s2, al_d2);
    hipLaunchKernelGGL(k_gather2, dim3((N_NODES + 3) / 4), dim3(256), 0, stream,
                       rowptr, sorted_src, xw2b, al_s2, al_d2, b2, out);
}

// Round 5
// 278.411 us; speedup vs baseline: 15.7941x; 1.1276x over previous
//
#include <hip/hip_runtime.h>
#include <math.h>

#define N_NODES 50000
#define E_EDGES 1600000
#define IN_CH   34
#define NEG     0.2f
#define NB      196          // coarse buckets: dst>>8
#define CAP     10000        // bucket capacity (E[8192], sigma~90)

static __device__ __forceinline__ unsigned short f2bf(float f) {
    unsigned int u = __float_as_uint(f);
    u += 0x7fffu + ((u >> 16) & 1u);
    return (unsigned short)(u >> 16);
}
static __device__ __forceinline__ float bflo(unsigned int u) {
    return __uint_as_float(u << 16);
}
static __device__ __forceinline__ float bfhi(unsigned int u) {
    return __uint_as_float(u & 0xffff0000u);
}
static __device__ __forceinline__ float lrelu_exp(float e) {
    return expf(e > 0.f ? e : NEG * e);
}

// 256-thread block exclusive scan. wsum = int[4] LDS scratch.
static __device__ __forceinline__ int scan256_excl(int v, int* wsum) {
    const int lane = threadIdx.x & 63, wv = threadIdx.x >> 6;
    int x = v;
    #pragma unroll
    for (int off = 1; off < 64; off <<= 1) {
        int y = __shfl_up(x, off);
        if (lane >= off) x += y;
    }
    if (lane == 63) wsum[wv] = x;
    __syncthreads();
    if (threadIdx.x < 4) {
        int s = wsum[threadIdx.x];
        #pragma unroll
        for (int off = 1; off < 4; off <<= 1) {
            int y = __shfl_up(s, off);
            if ((int)threadIdx.x >= off) s += y;
        }
        wsum[threadIdx.x] = s;
    }
    __syncthreads();
    const int woff = wv ? wsum[wv - 1] : 0;
    return woff + x - v;
}

// Init bucket cursors to strided bases.
__global__ __launch_bounds__(256) void k_init(int* __restrict__ gcur)
{
    const int t = threadIdx.x;
    if (t < NB) gcur[t] = t * CAP;
}

// Bin edges into bucket-strided `binned` ((dst<<16)|src). Single global read.
__global__ __launch_bounds__(256) void k_bin(
    const int* __restrict__ srcA, const int* __restrict__ dstA,
    int* __restrict__ gcur, unsigned int* __restrict__ binned)
{
    __shared__ unsigned int raw[8192];    // 32 KB (arrival order)
    __shared__ unsigned int ebuf[8192];   // 32 KB (bucket-ordered)
    __shared__ int cnt[256], loff[256], lcur[256], cur[256];
    __shared__ int wsum[4];
    const int tid = threadIdx.x;
    cnt[tid] = 0;
    __syncthreads();
    const int base = blockIdx.x * 8192;
    #pragma unroll
    for (int i = 0; i < 32; ++i) {
        const int e = base + i * 256 + tid;
        if (e < E_EDGES) {
            const int d = dstA[e], s = srcA[e];
            raw[i * 256 + tid] = ((unsigned int)d << 16) | (unsigned int)s;
            atomicAdd(&cnt[d >> 8], 1);
        }
    }
    __syncthreads();
    const int v = cnt[tid];
    const int excl = scan256_excl(v, wsum);
    loff[tid] = excl;
    lcur[tid] = excl;
    cur[tid] = (tid < NB && v > 0) ? atomicAdd(&gcur[tid], v) : 0;
    __syncthreads();
    const int mE = min(8192, E_EDGES - base);
    #pragma unroll
    for (int i = 0; i < 32; ++i) {
        const int p = i * 256 + tid;
        if (p < mE) {
            const unsigned int u = raw[p];
            const int q = atomicAdd(&lcur[u >> 24], 1);
            ebuf[q] = u;
        }
    }
    __syncthreads();
    #pragma unroll
    for (int i = 0; i < 32; ++i) {
        const int p = i * 256 + tid;
        if (p < mE) {
            const unsigned int u = ebuf[p];
            const int b = (int)(u >> 24);
            binned[cur[b] + (p - loff[b])] = u;
        }
    }
}

// Per-bucket fine sort (LDS-staged, one global read) -> sorted_src + rowspan.
__global__ __launch_bounds__(256) void k_fine(
    const int* __restrict__ gcur, const unsigned int* __restrict__ binned,
    int2* __restrict__ rowspan, int* __restrict__ sorted_src)
{
    __shared__ unsigned int sbin[CAP];    // 40 KB
    __shared__ int cnt[256], lcur[256];
    __shared__ int wsum[4];
    const int tid = threadIdx.x;
    const int b = blockIdx.x;
    const int bbase = b * CAP;
    const int cntb = gcur[b] - bbase;
    cnt[tid] = 0;
    __syncthreads();
    for (int p = tid; p < cntb; p += 256) {
        const unsigned int u = binned[bbase + p];
        sbin[p] = u;
        atomicAdd(&cnt[(u >> 16) & 255], 1);
    }
    __syncthreads();
    const int v = cnt[tid];
    const int excl = scan256_excl(v, wsum);
    const int node = b * 256 + tid;
    if (node < N_NODES) rowspan[node] = make_int2(bbase + excl, bbase + excl + v);
    lcur[tid] = excl;
    __syncthreads();
    for (int p = tid; p < cntb; p += 256) {
        const unsigned int u = sbin[p];
        const int q = atomicAdd(&lcur[(u >> 16) & 255], 1);
        sorted_src[bbase + q] = (int)(u & 0xffffu);
    }
}

// ---------------------------------------------------------------------------
// Layer 1 node pre-pass (register-tiled): xw1b = bf16(x @ W1) [N,128];
// logit halves al_s/al_d [N,2].
// ---------------------------------------------------------------------------
__global__ __launch_bounds__(256) void k_node1(
    const float* __restrict__ x, const float* __restrict__ W1,
    const float* __restrict__ a_src, const float* __restrict__ a_dst,
    unsigned short* __restrict__ xw1b,
    float* __restrict__ al_s, float* __restrict__ al_d)
{
    __shared__ float sW[IN_CH * 132];
    __shared__ float sx[32 * 35];
    __shared__ float sas[128], sad[128];
    const int tid = threadIdx.x;
    for (int i = tid; i < IN_CH * 128; i += 256) {
        int k = i >> 7, c = i & 127;
        sW[k * 132 + c] = W1[i];
    }
    if (tid < 128) { sas[tid] = a_src[tid]; sad[tid] = a_dst[tid]; }
    const int n0 = blockIdx.x * 32;
    for (int i = tid; i < 32 * IN_CH; i += 256) {
        int n = i / IN_CH, c = i - n * IN_CH;
        sx[n * 35 + c] = (n0 + n < N_NODES) ? x[n0 * IN_CH + i] : 0.f;
    }
    __syncthreads();

    const int tc = tid & 31, tn = tid >> 5;
    float acc[4][4] = {{0.f}};
    for (int k = 0; k < IN_CH; ++k) {
        const float4 wv = *reinterpret_cast<const float4*>(&sW[k * 132 + 4 * tc]);
        #pragma unroll
        for (int j = 0; j < 4; ++j) {
            const float hj = sx[(4 * tn + j) * 35 + k];
            acc[j][0] += hj * wv.x; acc[j][1] += hj * wv.y;
            acc[j][2] += hj * wv.z; acc[j][3] += hj * wv.w;
        }
    }
    #pragma unroll
    for (int j = 0; j < 4; ++j) {
        const int node = n0 + 4 * tn + j;
        float ps = 0.f, pd = 0.f;
        #pragma unroll
        for (int c = 0; c < 4; ++c) {
            ps += acc[j][c] * sas[4 * tc + c];
            pd += acc[j][c] * sad[4 * tc + c];
        }
        #pragma unroll
        for (int off = 1; off < 16; off <<= 1) {
            ps += __shfl_xor(ps, off);
            pd += __shfl_xor(pd, off);
        }
        if (node < N_NODES) {
            if ((tc & 15) == 0) {
                int h = tc >> 4;
                al_s[node * 2 + h] = ps;
                al_d[node * 2 + h] = pd;
            }
            ushort4 u;
            u.x = f2bf(acc[j][0]); u.y = f2bf(acc[j][1]);
            u.z = f2bf(acc[j][2]); u.w = f2bf(acc[j][3]);
            *reinterpret_cast<ushort4*>(&xw1b[node * 128 + 4 * tc]) = u;
        }
    }
}

// ---------------------------------------------------------------------------
// Layer 1 gather, paired edges: one wave per node. Lanes 0-31 serve edge j
// (uint2 -> cols 4li..4li+3), lanes 32-63 serve edge j+1. Cross-combine via
// shfl_xor(32). Fused finalize: h = relu(acc/den + b1).
// ---------------------------------------------------------------------------
__global__ __launch_bounds__(256) void k_gather1(
    const int2* __restrict__ rowspan, const int* __restrict__ sorted_src,
    const uint2* __restrict__ xw1p,           // 32 uint2 per row
    const float* __restrict__ al_s, const float* __restrict__ al_d,
    const float* __restrict__ b1, float* __restrict__ hbuf)
{
    __shared__ float4 ebuf[4][64];
    const int wave = threadIdx.x >> 6;
    const int lane = threadIdx.x & 63;
    const int node = (blockIdx.x * 256 + threadIdx.x) >> 6;
    if (node >= N_NODES) return;
    const int2 span = rowspan[node];
    const int li = lane & 31;                 // uint2 index within row
    const int hsel = lane >> 5;               // pair member (0/1)
    const bool hd0 = (li < 16);               // head of this lane's columns

    const float2 ald  = *reinterpret_cast<const float2*>(&al_d[node * 2]);
    const float2 als0 = *reinterpret_cast<const float2*>(&al_s[node * 2]);
    const float w0h0 = lrelu_exp(als0.x + ald.x);
    const float w0h1 = lrelu_exp(als0.y + ald.y);

    // self-loop: A-half accumulates, B-half weight 0
    const uint2 sv = xw1p[node * 32 + li];
    const float wself = (hsel == 0) ? (hd0 ? w0h0 : w0h1) : 0.f;
    float acc0 = wself * bflo(sv.x), acc1 = wself * bfhi(sv.x);
    float acc2 = wself * bflo(sv.y), acc3 = wself * bfhi(sv.y);
    float dv0 = 0.f, dv1 = 0.f;
    float4* eb = ebuf[wave];

    for (int base = span.x; base < span.y; base += 64) {
        const int rem = span.y - base;
        const int m = rem < 64 ? rem : 64;
        if (lane < m) {
            const int s = sorted_src[base + lane];
            const float2 als = *reinterpret_cast<const float2*>(&al_s[s * 2]);
            const float w0 = lrelu_exp(als.x + ald.x);
            const float w1 = lrelu_exp(als.y + ald.y);
            dv0 += w0; dv1 += w1;
            eb[lane] = make_float4(__int_as_float(s << 5), w0, w1, 0.f);
        } else if (lane == m && (m & 1)) {
            eb[m] = make_float4(__int_as_float(0), 0.f, 0.f, 0.f);  // pad pair
        }
        const int pairs = (m + 1) >> 1;
        int pr = 0;
        for (; pr + 4 <= pairs; pr += 4) {
            const float4 q0 = eb[2 * pr + 0 + hsel];
            const float4 q1 = eb[2 * pr + 2 + hsel];
            const float4 q2 = eb[2 * pr + 4 + hsel];
            const float4 q3 = eb[2 * pr + 6 + hsel];
            const uint2 v0 = xw1p[__float_as_int(q0.x) + li];
            const uint2 v1 = xw1p[__float_as_int(q1.x) + li];
            const uint2 v2 = xw1p[__float_as_int(q2.x) + li];
            const uint2 v3 = xw1p[__float_as_int(q3.x) + li];
            const float w0 = hd0 ? q0.y : q0.z;
            const float w1 = hd0 ? q1.y : q1.z;
            const float w2 = hd0 ? q2.y : q2.z;
            const float w3 = hd0 ? q3.y : q3.z;
            acc0 += w0 * bflo(v0.x); acc1 += w0 * bfhi(v0.x);
            acc2 += w0 * bflo(v0.y); acc3 += w0 * bfhi(v0.y);
            acc0 += w1 * bflo(v1.x); acc1 += w1 * bfhi(v1.x);
            acc2 += w1 * bflo(v1.y); acc3 += w1 * bfhi(v1.y);
            acc0 += w2 * bflo(v2.x); acc1 += w2 * bfhi(v2.x);
            acc2 += w2 * bflo(v2.y); acc3 += w2 * bfhi(v2.y);
            acc0 += w3 * bflo(v3.x); acc1 += w3 * bfhi(v3.x);
            acc2 += w3 * bflo(v3.y); acc3 += w3 * bfhi(v3.y);
        }
        for (; pr < pairs; ++pr) {
            const float4 q = eb[2 * pr + hsel];
            const uint2 v = xw1p[__float_as_int(q.x) + li];
            const float w = hd0 ? q.y : q.z;
            acc0 += w * bflo(v.x); acc1 += w * bfhi(v.x);
            acc2 += w * bflo(v.y); acc3 += w * bfhi(v.y);
        }
    }
    // combine pair halves
    acc0 += __shfl_xor(acc0, 32); acc1 += __shfl_xor(acc1, 32);
    acc2 += __shfl_xor(acc2, 32); acc3 += __shfl_xor(acc3, 32);
    #pragma unroll
    for (int off = 32; off; off >>= 1) {
        dv0 += __shfl_xor(dv0, off);
        dv1 += __shfl_xor(dv1, off);
    }
    if (lane < 32) {
        const float den = hd0 ? (dv0 + w0h0) : (dv1 + w0h1);
        const float4 bv = *reinterpret_cast<const float4*>(&b1[4 * li]);
        float o0 = acc0 / den + bv.x, o1 = acc1 / den + bv.y;
        float o2 = acc2 / den + bv.z, o3 = acc3 / den + bv.w;
        o0 = o0 > 0.f ? o0 : 0.f; o1 = o1 > 0.f ? o1 : 0.f;
        o2 = o2 > 0.f ? o2 : 0.f; o3 = o3 > 0.f ? o3 : 0.f;
        *reinterpret_cast<float4*>(&hbuf[node * 128 + 4 * li]) =
            make_float4(o0, o1, o2, o3);
    }
}

// ---------------------------------------------------------------------------
// Layer 2 node pre-pass (register-tiled): xw2b = bf16(h @ W2) [N,64].
// ---------------------------------------------------------------------------
__global__ __launch_bounds__(256) void k_node2(
    const float* __restrict__ hbuf, const float* __restrict__ W2,
    const float* __restrict__ a_src, const float* __restrict__ a_dst,
    unsigned short* __restrict__ xw2b, float* __restrict__ al_s, float* __restrict__ al_d)
{
    __shared__ float sW[128 * 64];
    __shared__ float sh[64 * 129];
    __shared__ float sas[64], sad[64];
    const int tid = threadIdx.x;
    for (int i = tid; i < 128 * 64; i += 256) sW[i] = W2[i];
    if (tid < 64) { sas[tid] = a_src[tid]; sad[tid] = a_dst[tid]; }
    const int n0 = blockIdx.x * 64;
    for (int i = tid; i < 64 * 128; i += 256) {
        int n = i >> 7, c = i & 127;
        sh[n * 129 + c] = (n0 + n < N_NODES) ? hbuf[(long)(n0 + n) * 128 + c] : 0.f;
    }
    __syncthreads();

    const int tc = tid & 15, tn = tid >> 4;
    float acc[4][4] = {{0.f}};
    for (int k = 0; k < 128; ++k) {
        const float4 wv = *reinterpret_cast<const float4*>(&sW[k * 64 + 4 * tc]);
        #pragma unroll
        for (int j = 0; j < 4; ++j) {
            const float hj = sh[(4 * tn + j) * 129 + k];
            acc[j][0] += hj * wv.x; acc[j][1] += hj * wv.y;
            acc[j][2] += hj * wv.z; acc[j][3] += hj * wv.w;
        }
    }
    #pragma unroll
    for (int j = 0; j < 4; ++j) {
        const int node = n0 + 4 * tn + j;
        float ps = 0.f, pd = 0.f;
        #pragma unroll
        for (int c = 0; c < 4; ++c) {
            ps += acc[j][c] * sas[4 * tc + c];
            pd += acc[j][c] * sad[4 * tc + c];
        }
        #pragma unroll
        for (int off = 1; off < 16; off <<= 1) {
            ps += __shfl_xor(ps, off);
            pd += __shfl_xor(pd, off);
        }
        if (node < N_NODES) {
            if (tc == 0) { al_s[node] = ps; al_d[node] = pd; }
            ushort4 u;
            u.x = f2bf(acc[j][0]); u.y = f2bf(acc[j][1]);
            u.z = f2bf(acc[j][2]); u.w = f2bf(acc[j][3]);
            *reinterpret_cast<ushort4*>(&xw2b[node * 64 + 4 * tc]) = u;
        }
    }
}

// ---------------------------------------------------------------------------
// Layer 2 gather, paired edges: lanes 0-31 edge j (uint -> cols 2li,2li+1),
// lanes 32-63 edge j+1. Fused finalize: out = acc/den + b2.
// ---------------------------------------------------------------------------
__global__ __launch_bounds__(256) void k_gather2(
    const int2* __restrict__ rowspan, const int* __restrict__ sorted_src,
    const unsigned int* __restrict__ xw2p,    // 32 uints per row
    const float* __restrict__ al_s, const float* __restrict__ al_d,
    const float* __restrict__ b2, float* __restrict__ out)
{
    __shared__ float2 ebuf[4][64];
    const int wave = threadIdx.x >> 6;
    const int lane = threadIdx.x & 63;
    const int node = (blockIdx.x * 256 + threadIdx.x) >> 6;
    if (node >= N_NODES) return;
    const int2 span = rowspan[node];
    const int li = lane & 31;
    const int hsel = lane >> 5;

    const float ald = al_d[node];
    const float w0s = lrelu_exp(al_s[node] + ald);
    const unsigned int sv = xw2p[node * 32 + li];
    const float wself = (hsel == 0) ? w0s : 0.f;
    float acc0 = wself * bflo(sv), acc1 = wself * bfhi(sv);
    float dv = 0.f;
    float2* eb = ebuf[wave];

    for (int base = span.x; base < span.y; base += 64) {
        const int rem = span.y - base;
        const int m = rem < 64 ? rem : 64;
        if (lane < m) {
            const int s = sorted_src[base + lane];
            const float w = lrelu_exp(al_s[s] + ald);
            dv += w;
            eb[lane] = make_float2(__int_as_float(s << 5), w);
        } else if (lane == m && (m & 1)) {
            eb[m] = make_float2(__int_as_float(0), 0.f);
        }
        const int pairs = (m + 1) >> 1;
        int pr = 0;
        for (; pr + 4 <= pairs; pr += 4) {
            const float2 q0 = eb[2 * pr + 0 + hsel];
            const float2 q1 = eb[2 * pr + 2 + hsel];
            const float2 q2 = eb[2 * pr + 4 + hsel];
            const float2 q3 = eb[2 * pr + 6 + hsel];
            const unsigned int v0 = xw2p[__float_as_int(q0.x) + li];
            const unsigned int v1 = xw2p[__float_as_int(q1.x) + li];
            const unsigned int v2 = xw2p[__float_as_int(q2.x) + li];
            const unsigned int v3 = xw2p[__float_as_int(q3.x) + li];
            acc0 += q0.y * bflo(v0); acc1 += q0.y * bfhi(v0);
            acc0 += q1.y * bflo(v1); acc1 += q1.y * bfhi(v1);
            acc0 += q2.y * bflo(v2); acc1 += q2.y * bfhi(v2);
            acc0 += q3.y * bflo(v3); acc1 += q3.y * bfhi(v3);
        }
        for (; pr < pairs; ++pr) {
            const float2 q = eb[2 * pr + hsel];
            const unsigned int v = xw2p[__float_as_int(q.x) + li];
            acc0 += q.y * bflo(v); acc1 += q.y * bfhi(v);
        }
    }
    acc0 += __shfl_xor(acc0, 32); acc1 += __shfl_xor(acc1, 32);
    #pragma unroll
    for (int off = 32; off; off >>= 1) dv += __shfl_xor(dv, off);
    if (lane < 32) {
        const float den = dv + w0s;
        const float2 bv = *reinterpret_cast<const float2*>(&b2[2 * li]);
        *reinterpret_cast<float2*>(&out[node * 64 + 2 * li]) =
            make_float2(acc0 / den + bv.x, acc1 / den + bv.y);
    }
}

extern "C" void kernel_launch(void* const* d_in, const int* in_sizes, int n_in,
                              void* d_out, int out_size, void* d_ws, size_t ws_size,
                              hipStream_t stream)
{
    const float* x   = (const float*)d_in[0];
    const int*   ei  = (const int*)d_in[1];
    const float* W1  = (const float*)d_in[2];
    const float* as1 = (const float*)d_in[3];
    const float* ad1 = (const float*)d_in[4];
    const float* b1  = (const float*)d_in[5];
    const float* W2  = (const float*)d_in[6];
    const float* as2 = (const float*)d_in[7];
    const float* ad2 = (const float*)d_in[8];
    const float* b2  = (const float*)d_in[9];
    float* out = (float*)d_out;

    const int* srcA = ei;
    const int* dstA = ei + E_EDGES;

    // Workspace layout (bytes). Total 54,251,648 B.
    char* ws = (char*)d_ws;
    int2*  rowspan    = (int2*)(ws);                         // 400 KB (pad 409,600)
    int*   sorted_src = (int*)(ws + 409600);                 // 7.84 MB
    int*   gcur       = (int*)(ws + 8249600);                // NB ints (pad 2 KB)
    float* al_s1      = (float*)(ws + 8251648);              // 400 KB
    float* al_d1      = (float*)(ws + 8651648);              // 400 KB
    float* al_s2      = (float*)(ws + 9051648);              // 200 KB
    float* al_d2      = (float*)(ws + 9251648);              // 200 KB
    unsigned short* xw1b = (unsigned short*)(ws + 9451648);  // 12.8 MB bf16
    float* hbuf       = (float*)(ws + 22251648);             // 25.6 MB fp32
    unsigned int* binned = (unsigned int*)hbuf;              // alias: dead before gather1
    unsigned short* xw2b = (unsigned short*)(ws + 47851648); // 6.4 MB bf16

    hipLaunchKernelGGL(k_init, dim3(1), dim3(256), 0, stream, gcur);
    hipLaunchKernelGGL(k_bin, dim3((E_EDGES + 8191) / 8192), dim3(256), 0, stream,
                       srcA, dstA, gcur, binned);
    hipLaunchKernelGGL(k_fine, dim3(NB), dim3(256), 0, stream,
                       gcur, binned, rowspan, sorted_src);

    hipLaunchKernelGGL(k_node1, dim3((N_NODES + 31) / 32), dim3(256), 0, stream,
                       x, W1, as1, ad1, xw1b, al_s1, al_d1);
    hipLaunchKernelGGL(k_gather1, dim3((N_NODES + 3) / 4), dim3(256), 0, stream,
                       rowspan, sorted_src, (const uint2*)xw1b,
                       al_s1, al_d1, b1, hbuf);
    hipLaunchKernelGGL(k_node2, dim3((N_NODES + 63) / 64), dim3(256), 0, stream,
                       hbuf, W2, as2, ad2, xw2b, al_s2, al_d2);
    hipLaunchKernelGGL(k_gather2, dim3((N_NODES + 3) / 4), dim3(256), 0, stream,
                       rowspan, sorted_src, (const unsigned int*)xw2b,
                       al_s2, al_d2, b2, out);
}

// Round 6
// 268.235 us; speedup vs baseline: 16.3933x; 1.0379x over previous
//
#include <hip/hip_runtime.h>
#include <math.h>

#define N_NODES 50000
#define E_EDGES 1600000
#define IN_CH   34
#define NEG     0.2f
#define NB      196          // coarse buckets: dst>>8
#define CAP     10000        // bucket capacity (E[8192], sigma~90)

typedef __attribute__((ext_vector_type(2))) float fv2;

static __device__ __forceinline__ unsigned short f2bf(float f) {
    unsigned int u = __float_as_uint(f);
    u += 0x7fffu + ((u >> 16) & 1u);
    return (unsigned short)(u >> 16);
}
static __device__ __forceinline__ float bflo(unsigned int u) {
    return __uint_as_float(u << 16);
}
static __device__ __forceinline__ float bfhi(unsigned int u) {
    return __uint_as_float(u & 0xffff0000u);
}
static __device__ __forceinline__ float lrelu_exp(float e) {
    return expf(e > 0.f ? e : NEG * e);
}

// 256-thread block exclusive scan. wsum = int[4] LDS scratch.
static __device__ __forceinline__ int scan256_excl(int v, int* wsum) {
    const int lane = threadIdx.x & 63, wv = threadIdx.x >> 6;
    int x = v;
    #pragma unroll
    for (int off = 1; off < 64; off <<= 1) {
        int y = __shfl_up(x, off);
        if (lane >= off) x += y;
    }
    if (lane == 63) wsum[wv] = x;
    __syncthreads();
    if (threadIdx.x < 4) {
        int s = wsum[threadIdx.x];
        #pragma unroll
        for (int off = 1; off < 4; off <<= 1) {
            int y = __shfl_up(s, off);
            if ((int)threadIdx.x >= off) s += y;
        }
        wsum[threadIdx.x] = s;
    }
    __syncthreads();
    const int woff = wv ? wsum[wv - 1] : 0;
    return woff + x - v;
}

// ---------------------------------------------------------------------------
// Fused: blocks [0,NB) bin edges into bucket-strided `binned`; blocks [NB,..)
// run the layer-1 node GEMM (independent work, overlaps the LDS-heavy binning).
// gcur must be zeroed beforehand (memset); bucket base = b*CAP + atomic count.
// ---------------------------------------------------------------------------
__global__ __launch_bounds__(256) void k_bin_node1(
    const int* __restrict__ srcA, const int* __restrict__ dstA,
    int* __restrict__ gcur, unsigned int* __restrict__ binned,
    const float* __restrict__ x, const float* __restrict__ W1,
    const float* __restrict__ a_src, const float* __restrict__ a_dst,
    unsigned short* __restrict__ xw1b,
    float* __restrict__ al_s, float* __restrict__ al_d)
{
    __shared__ __align__(16) char sm[69664];
    const int tid = threadIdx.x;

    if (blockIdx.x < NB) {
        // ---- binning role ----
        unsigned int* raw  = (unsigned int*)sm;            // 32768 B
        unsigned int* ebuf = (unsigned int*)(sm + 32768);  // 32768 B
        int* cnt  = (int*)(sm + 65536);
        int* loff = (int*)(sm + 66560);
        int* lcur = (int*)(sm + 67584);
        int* cur  = (int*)(sm + 68608);
        int* wsum = (int*)(sm + 69632);
        cnt[tid] = 0;
        __syncthreads();
        const int base = blockIdx.x * 8192;
        #pragma unroll
        for (int i = 0; i < 32; ++i) {
            const int e = base + i * 256 + tid;
            if (e < E_EDGES) {
                const int d = dstA[e], s = srcA[e];
                raw[i * 256 + tid] = ((unsigned int)d << 16) | (unsigned int)s;
                atomicAdd(&cnt[d >> 8], 1);
            }
        }
        __syncthreads();
        const int v = cnt[tid];
        const int excl = scan256_excl(v, wsum);
        loff[tid] = excl;
        lcur[tid] = excl;
        cur[tid] = (tid < NB && v > 0) ? (tid * CAP + atomicAdd(&gcur[tid], v)) : 0;
        __syncthreads();
        const int mE = min(8192, E_EDGES - base);
        #pragma unroll
        for (int i = 0; i < 32; ++i) {
            const int p = i * 256 + tid;
            if (p < mE) {
                const unsigned int u = raw[p];
                const int q = atomicAdd(&lcur[u >> 24], 1);
                ebuf[q] = u;
            }
        }
        __syncthreads();
        #pragma unroll
        for (int i = 0; i < 32; ++i) {
            const int p = i * 256 + tid;
            if (p < mE) {
                const unsigned int u = ebuf[p];
                const int b = (int)(u >> 24);
                binned[cur[b] + (p - loff[b])] = u;
            }
        }
    } else {
        // ---- node1 role: xw1b = bf16(x @ W1), logits al_s/al_d ----
        float* sW  = (float*)sm;                 // 34*132*4 = 17952 B
        float* sx  = (float*)(sm + 17952);       // 32*35*4  = 4480 B
        float* sas = (float*)(sm + 22432);       // 512 B
        float* sad = (float*)(sm + 22944);       // 512 B
        for (int i = tid; i < IN_CH * 128; i += 256) {
            int k = i >> 7, c = i & 127;
            sW[k * 132 + c] = W1[i];
        }
        if (tid < 128) { sas[tid] = a_src[tid]; sad[tid] = a_dst[tid]; }
        const int n0 = (blockIdx.x - NB) * 32;
        for (int i = tid; i < 32 * IN_CH; i += 256) {
            int n = i / IN_CH;
            sx[n * 35 + (i - n * IN_CH)] = (n0 + n < N_NODES) ? x[n0 * IN_CH + i] : 0.f;
        }
        __syncthreads();

        const int tc = tid & 31, tn = tid >> 5;
        float acc[4][4] = {{0.f}};
        for (int k = 0; k < IN_CH; ++k) {
            const float4 wv = *reinterpret_cast<const float4*>(&sW[k * 132 + 4 * tc]);
            #pragma unroll
            for (int j = 0; j < 4; ++j) {
                const float hj = sx[(4 * tn + j) * 35 + k];
                acc[j][0] += hj * wv.x; acc[j][1] += hj * wv.y;
                acc[j][2] += hj * wv.z; acc[j][3] += hj * wv.w;
            }
        }
        #pragma unroll
        for (int j = 0; j < 4; ++j) {
            const int node = n0 + 4 * tn + j;
            float ps = 0.f, pd = 0.f;
            #pragma unroll
            for (int c = 0; c < 4; ++c) {
                ps += acc[j][c] * sas[4 * tc + c];
                pd += acc[j][c] * sad[4 * tc + c];
            }
            #pragma unroll
            for (int off = 1; off < 16; off <<= 1) {
                ps += __shfl_xor(ps, off);
                pd += __shfl_xor(pd, off);
            }
            if (node < N_NODES) {
                if ((tc & 15) == 0) {
                    int h = tc >> 4;
                    al_s[node * 2 + h] = ps;
                    al_d[node * 2 + h] = pd;
                }
                ushort4 u;
                u.x = f2bf(acc[j][0]); u.y = f2bf(acc[j][1]);
                u.z = f2bf(acc[j][2]); u.w = f2bf(acc[j][3]);
                *reinterpret_cast<ushort4*>(&xw1b[node * 128 + 4 * tc]) = u;
            }
        }
    }
}

// Per-bucket fine sort (LDS-staged) -> sorted_src + rowspan.
__global__ __launch_bounds__(256) void k_fine(
    const int* __restrict__ gcur, const unsigned int* __restrict__ binned,
    int2* __restrict__ rowspan, int* __restrict__ sorted_src)
{
    __shared__ unsigned int sbin[CAP];    // 40 KB
    __shared__ int cnt[256], lcur[256];
    __shared__ int wsum[4];
    const int tid = threadIdx.x;
    const int b = blockIdx.x;
    const int bbase = b * CAP;
    const int cntb = gcur[b];
    cnt[tid] = 0;
    __syncthreads();
    for (int p = tid; p < cntb; p += 256) {
        const unsigned int u = binned[bbase + p];
        sbin[p] = u;
        atomicAdd(&cnt[(u >> 16) & 255], 1);
    }
    __syncthreads();
    const int v = cnt[tid];
    const int excl = scan256_excl(v, wsum);
    const int node = b * 256 + tid;
    if (node < N_NODES) rowspan[node] = make_int2(bbase + excl, bbase + excl + v);
    lcur[tid] = excl;
    __syncthreads();
    for (int p = tid; p < cntb; p += 256) {
        const unsigned int u = sbin[p];
        const int q = atomicAdd(&lcur[(u >> 16) & 255], 1);
        sorted_src[bbase + q] = (int)(u & 0xffffu);
    }
}

// ---------------------------------------------------------------------------
// Layer 1 gather: one wave per node; lane owns cols 2l,2l+1 (one uint/row).
// Per-head (offset,weight) pair-packed LDS arrays -> one ds_read_b128 per
// edge pair, no per-edge selects. fv2 accumulators (packed f32 fma).
// ---------------------------------------------------------------------------
__global__ __launch_bounds__(256) void k_gather1(
    const int2* __restrict__ rowspan, const int* __restrict__ sorted_src,
    const unsigned int* __restrict__ xw1u,    // 64 uints per row
    const float* __restrict__ al_s, const float* __restrict__ al_d,
    const float* __restrict__ b1, float* __restrict__ hbuf)
{
    __shared__ float4 AB[2][4][32];           // [head][wave][pair]=(offA,wA,offB,wB)
    const int wave = threadIdx.x >> 6;
    const int lane = threadIdx.x & 63;
    const int node = (blockIdx.x * 256 + threadIdx.x) >> 6;
    if (node >= N_NODES) return;
    const int2 span = rowspan[node];
    const int head = lane >> 5;

    const float2 ald  = *reinterpret_cast<const float2*>(&al_d[node * 2]);
    const float2 als0 = *reinterpret_cast<const float2*>(&al_s[node * 2]);
    const float w0h0 = lrelu_exp(als0.x + ald.x);
    const float w0h1 = lrelu_exp(als0.y + ald.y);
    const float wself = head ? w0h1 : w0h0;

    const unsigned int su = xw1u[node * 64 + lane];
    fv2 accX = { wself * bflo(su), wself * bfhi(su) };
    fv2 accY = { 0.f, 0.f };
    float dv0 = 0.f, dv1 = 0.f;
    const float4* ABh = AB[head][wave];

    for (int base = span.x; base < span.y; base += 64) {
        const int rem = span.y - base;
        const int m = rem < 64 ? rem : 64;
        const int mp = (m + 1) & ~1;
        if (lane < m) {
            const int s = sorted_src[base + lane];
            const float2 als = *reinterpret_cast<const float2*>(&al_s[s * 2]);
            const float w0 = lrelu_exp(als.x + ald.x);
            const float w1 = lrelu_exp(als.y + ald.y);
            dv0 += w0; dv1 += w1;
            const float offf = __int_as_float(s << 6);
            ((float2*)&AB[0][wave][lane >> 1])[lane & 1] = make_float2(offf, w0);
            ((float2*)&AB[1][wave][lane >> 1])[lane & 1] = make_float2(offf, w1);
        } else if (lane < mp) {
            const float offf = __int_as_float(node << 6);
            ((float2*)&AB[0][wave][lane >> 1])[lane & 1] = make_float2(offf, 0.f);
            ((float2*)&AB[1][wave][lane >> 1])[lane & 1] = make_float2(offf, 0.f);
        }
        const int P = mp >> 1;
        int p = 0;
        for (; p + 4 <= P; p += 4) {
            const float4 q0 = ABh[p + 0];
            const float4 q1 = ABh[p + 1];
            const float4 q2 = ABh[p + 2];
            const float4 q3 = ABh[p + 3];
            const unsigned int a0 = xw1u[__float_as_int(q0.x) + lane];
            const unsigned int b0 = xw1u[__float_as_int(q0.z) + lane];
            const unsigned int a1 = xw1u[__float_as_int(q1.x) + lane];
            const unsigned int b1v = xw1u[__float_as_int(q1.z) + lane];
            const unsigned int a2 = xw1u[__float_as_int(q2.x) + lane];
            const unsigned int b2 = xw1u[__float_as_int(q2.z) + lane];
            const unsigned int a3 = xw1u[__float_as_int(q3.x) + lane];
            const unsigned int b3 = xw1u[__float_as_int(q3.z) + lane];
            fv2 f;
            f.x = bflo(a0); f.y = bfhi(a0); accX += f * q0.y;
            f.x = bflo(b0); f.y = bfhi(b0); accY += f * q0.w;
            f.x = bflo(a1); f.y = bfhi(a1); accX += f * q1.y;
            f.x = bflo(b1v); f.y = bfhi(b1v); accY += f * q1.w;
            f.x = bflo(a2); f.y = bfhi(a2); accX += f * q2.y;
            f.x = bflo(b2); f.y = bfhi(b2); accY += f * q2.w;
            f.x = bflo(a3); f.y = bfhi(a3); accX += f * q3.y;
            f.x = bflo(b3); f.y = bfhi(b3); accY += f * q3.w;
        }
        for (; p < P; ++p) {
            const float4 q = ABh[p];
            const unsigned int a = xw1u[__float_as_int(q.x) + lane];
            const unsigned int b = xw1u[__float_as_int(q.z) + lane];
            fv2 f;
            f.x = bflo(a); f.y = bfhi(a); accX += f * q.y;
            f.x = bflo(b); f.y = bfhi(b); accY += f * q.w;
        }
    }
    accX += accY;
    #pragma unroll
    for (int off = 32; off; off >>= 1) {
        dv0 += __shfl_xor(dv0, off);
        dv1 += __shfl_xor(dv1, off);
    }
    const float den = head ? (dv1 + w0h1) : (dv0 + w0h0);
    const float2 bv = *reinterpret_cast<const float2*>(&b1[2 * lane]);
    float o0 = accX.x / den + bv.x;
    float o1 = accX.y / den + bv.y;
    o0 = o0 > 0.f ? o0 : 0.f;
    o1 = o1 > 0.f ? o1 : 0.f;
    *reinterpret_cast<float2*>(&hbuf[node * 128 + 2 * lane]) = make_float2(o0, o1);
}

// ---------------------------------------------------------------------------
// Layer 2 node pre-pass (register-tiled): xw2b = bf16(h @ W2) [N,64].
// ---------------------------------------------------------------------------
__global__ __launch_bounds__(256) void k_node2(
    const float* __restrict__ hbuf, const float* __restrict__ W2,
    const float* __restrict__ a_src, const float* __restrict__ a_dst,
    unsigned short* __restrict__ xw2b, float* __restrict__ al_s, float* __restrict__ al_d)
{
    __shared__ float sW[128 * 64];
    __shared__ float sh[64 * 129];
    __shared__ float sas[64], sad[64];
    const int tid = threadIdx.x;
    for (int i = tid; i < 128 * 64; i += 256) sW[i] = W2[i];
    if (tid < 64) { sas[tid] = a_src[tid]; sad[tid] = a_dst[tid]; }
    const int n0 = blockIdx.x * 64;
    for (int i = tid; i < 64 * 128; i += 256) {
        int n = i >> 7, c = i & 127;
        sh[n * 129 + c] = (n0 + n < N_NODES) ? hbuf[(long)(n0 + n) * 128 + c] : 0.f;
    }
    __syncthreads();

    const int tc = tid & 15, tn = tid >> 4;
    float acc[4][4] = {{0.f}};
    for (int k = 0; k < 128; ++k) {
        const float4 wv = *reinterpret_cast<const float4*>(&sW[k * 64 + 4 * tc]);
        #pragma unroll
        for (int j = 0; j < 4; ++j) {
            const float hj = sh[(4 * tn + j) * 129 + k];
            acc[j][0] += hj * wv.x; acc[j][1] += hj * wv.y;
            acc[j][2] += hj * wv.z; acc[j][3] += hj * wv.w;
        }
    }
    #pragma unroll
    for (int j = 0; j < 4; ++j) {
        const int node = n0 + 4 * tn + j;
        float ps = 0.f, pd = 0.f;
        #pragma unroll
        for (int c = 0; c < 4; ++c) {
            ps += acc[j][c] * sas[4 * tc + c];
            pd += acc[j][c] * sad[4 * tc + c];
        }
        #pragma unroll
        for (int off = 1; off < 16; off <<= 1) {
            ps += __shfl_xor(ps, off);
            pd += __shfl_xor(pd, off);
        }
        if (node < N_NODES) {
            if (tc == 0) { al_s[node] = ps; al_d[node] = pd; }
            ushort4 u;
            u.x = f2bf(acc[j][0]); u.y = f2bf(acc[j][1]);
            u.z = f2bf(acc[j][2]); u.w = f2bf(acc[j][3]);
            *reinterpret_cast<ushort4*>(&xw2b[node * 64 + 4 * tc]) = u;
        }
    }
}

// ---------------------------------------------------------------------------
// Layer 2 gather: half-wave per edge pair (4 edges/step), pair-packed
// (offset,weight) LDS, fv2 accumulators. out = acc/den + b2.
// ---------------------------------------------------------------------------
__global__ __launch_bounds__(256) void k_gather2(
    const int2* __restrict__ rowspan, const int* __restrict__ sorted_src,
    const unsigned int* __restrict__ xw2u,    // 32 uints per row
    const float* __restrict__ al_s, const float* __restrict__ al_d,
    const float* __restrict__ b2, float* __restrict__ out)
{
    __shared__ float4 AB[4][32];              // [wave][pair]=(offA,wA,offB,wB)
    const int wave = threadIdx.x >> 6;
    const int lane = threadIdx.x & 63;
    const int node = (blockIdx.x * 256 + threadIdx.x) >> 6;
    if (node >= N_NODES) return;
    const int2 span = rowspan[node];
    const int li = lane & 31, hsel = lane >> 5;

    const float ald = al_d[node];
    const float w0s = lrelu_exp(al_s[node] + ald);
    const unsigned int su = xw2u[node * 32 + li];
    const float wself = hsel ? 0.f : w0s;
    fv2 acc = { wself * bflo(su), wself * bfhi(su) };
    float dv = 0.f;
    const float4* ABw = AB[wave];

    for (int base = span.x; base < span.y; base += 64) {
        const int rem = span.y - base;
        const int m = rem < 64 ? rem : 64;
        const int mp = (m + 3) & ~3;
        if (lane < m) {
            const int s = sorted_src[base + lane];
            const float w = lrelu_exp(al_s[s] + ald);
            dv += w;
            ((float2*)&AB[wave][lane >> 1])[lane & 1] =
                make_float2(__int_as_float(s << 5), w);
        } else if (lane < mp) {
            ((float2*)&AB[wave][lane >> 1])[lane & 1] =
                make_float2(__int_as_float(node << 5), 0.f);
        }
        const int P = mp >> 1;                // even
        int p = hsel;
        for (; p + 2 < P; p += 4) {
            const float4 qA = ABw[p];
            const float4 qB = ABw[p + 2];
            const unsigned int aA = xw2u[__float_as_int(qA.x) + li];
            const unsigned int bA = xw2u[__float_as_int(qA.z) + li];
            const unsigned int aB = xw2u[__float_as_int(qB.x) + li];
            const unsigned int bB = xw2u[__float_as_int(qB.z) + li];
            fv2 f;
            f.x = bflo(aA); f.y = bfhi(aA); acc += f * qA.y;
            f.x = bflo(bA); f.y = bfhi(bA); acc += f * qA.w;
            f.x = bflo(aB); f.y = bfhi(aB); acc += f * qB.y;
            f.x = bflo(bB); f.y = bfhi(bB); acc += f * qB.w;
        }
        for (; p < P; p += 2) {
            const float4 q = ABw[p];
            const unsigned int a = xw2u[__float_as_int(q.x) + li];
            const unsigned int b = xw2u[__float_as_int(q.z) + li];
            fv2 f;
            f.x = bflo(a); f.y = bfhi(a); acc += f * q.y;
            f.x = bflo(b); f.y = bfhi(b); acc += f * q.w;
        }
    }
    acc.x += __shfl_xor(acc.x, 32);
    acc.y += __shfl_xor(acc.y, 32);
    #pragma unroll
    for (int off = 32; off; off >>= 1) dv += __shfl_xor(dv, off);
    if (lane < 32) {
        const float den = dv + w0s;
        const float2 bv = *reinterpret_cast<const float2*>(&b2[2 * li]);
        *reinterpret_cast<float2*>(&out[node * 64 + 2 * li]) =
            make_float2(acc.x / den + bv.x, acc.y / den + bv.y);
    }
}

extern "C" void kernel_launch(void* const* d_in, const int* in_sizes, int n_in,
                              void* d_out, int out_size, void* d_ws, size_t ws_size,
                              hipStream_t stream)
{
    const float* x   = (const float*)d_in[0];
    const int*   ei  = (const int*)d_in[1];
    const float* W1  = (const float*)d_in[2];
    const float* as1 = (const float*)d_in[3];
    const float* ad1 = (const float*)d_in[4];
    const float* b1  = (const float*)d_in[5];
    const float* W2  = (const float*)d_in[6];
    const float* as2 = (const float*)d_in[7];
    const float* ad2 = (const float*)d_in[8];
    const float* b2  = (const float*)d_in[9];
    float* out = (float*)d_out;

    const int* srcA = ei;
    const int* dstA = ei + E_EDGES;

    // Workspace layout (bytes). Total 54,251,648 B.
    char* ws = (char*)d_ws;
    int2*  rowspan    = (int2*)(ws);                         // 400 KB (pad 409,600)
    int*   sorted_src = (int*)(ws + 409600);                 // 7.84 MB
    int*   gcur       = (int*)(ws + 8249600);                // NB ints (pad 2 KB)
    float* al_s1      = (float*)(ws + 8251648);              // 400 KB
    float* al_d1      = (float*)(ws + 8651648);              // 400 KB
    float* al_s2      = (float*)(ws + 9051648);              // 200 KB
    float* al_d2      = (float*)(ws + 9251648);              // 200 KB
    unsigned short* xw1b = (unsigned short*)(ws + 9451648);  // 12.8 MB bf16
    float* hbuf       = (float*)(ws + 22251648);             // 25.6 MB fp32
    unsigned int* binned = (unsigned int*)hbuf;              // alias: dead before gather1
    unsigned short* xw2b = (unsigned short*)(ws + 47851648); // 6.4 MB bf16

    hipMemsetAsync(gcur, 0, NB * sizeof(int), stream);
    hipLaunchKernelGGL(k_bin_node1, dim3(NB + (N_NODES + 31) / 32), dim3(256), 0, stream,
                       srcA, dstA, gcur, binned,
                       x, W1, as1, ad1, xw1b, al_s1, al_d1);
    hipLaunchKernelGGL(k_fine, dim3(NB), dim3(256), 0, stream,
                       gcur, binned, rowspan, sorted_src);
    hipLaunchKernelGGL(k_gather1, dim3((N_NODES + 3) / 4), dim3(256), 0, stream,
                       rowspan, sorted_src, (const unsigned int*)xw1b,
                       al_s1, al_d1, b1, hbuf);
    hipLaunchKernelGGL(k_node2, dim3((N_NODES + 63) / 64), dim3(256), 0, stream,
                       hbuf, W2, as2, ad2, xw2b, al_s2, al_d2);
    hipLaunchKernelGGL(k_gather2, dim3((N_NODES + 3) / 4), dim3(256), 0, stream,
                       rowspan, sorted_src, (const unsigned int*)xw2b,
                       al_s2, al_d2, b2, out);
}